// Round 10
// baseline (238.931 us; speedup 1.0000x reference)
//
#include <hip/hip_runtime.h>
#include <hip/hip_fp16.h>

constexpr int F_IN = 128;
constexpr int KC   = 128;   // K_CLUST == F_EMB == 128
constexpr int F2   = 256;   // K_CLUST + F_EMB
constexpr int NB_COARSE = 256;   // partial tiles per output
constexpr int NSPLIT = 8;        // t-axis split in coarse reduce stage 1
constexpr int NBLK_SORT = 256;   // blocks in bin-count / bin-place passes
constexpr int BIN_SHIFT = 7;     // 128 rows per bin
constexpr int MAXBIN = 512;      // ceil(65536/128)
constexpr int LR = 40;           // LDS row stride (fp16 units); 80B = 5*16B
// col segment = col>>13 (3 bits): 8192 rows * 256 B fp8 = 2 MB -> L2-resident
constexpr int SEG_BITS = 3;

typedef _Float16 f16x8 __attribute__((ext_vector_type(8)));
typedef float    f32x4 __attribute__((ext_vector_type(4)));
typedef float    f32x2 __attribute__((ext_vector_type(2)));

// ---------- fp16 helpers ----------
__device__ __forceinline__ unsigned int f2_to_h2u(float x, float y) {
    union { __half2 h; unsigned int i; } c;
    c.h = __floats2half2_rn(x, y);
    return c.i;
}
__device__ __forceinline__ float pe_val(unsigned int pe) {
    return __half2float(__ushort_as_half((unsigned short)(pe & 0xffffu)));
}

// ---------- fp8 e4m3fn helpers ----------
__device__ __forceinline__ unsigned char f32_to_fp8(float f) {
    union { __half h; unsigned short u; } c; c.h = __float2half_rn(f);
    unsigned short h = c.u;
    unsigned int s = (h >> 8) & 0x80u;
    int e5 = (h >> 10) & 0x1f;
    if (e5 < 9) return (unsigned char)s;
    unsigned int c7 = ((unsigned int)(e5 - 8) << 3) | ((h >> 7) & 7u);
    unsigned int rem = h & 0x7fu;
    c7 += (rem > 0x40u) || ((rem == 0x40u) && (c7 & 1u));
    if (c7 > 0x7eu) c7 = 0x7eu;
    return (unsigned char)(s | c7);
}
__device__ __forceinline__ float4 fp8x4_dec(unsigned int u) {
#if __has_builtin(__builtin_amdgcn_cvt_pk_f32_fp8)
    f32x2 lo = __builtin_amdgcn_cvt_pk_f32_fp8((int)u, false);
    f32x2 hi = __builtin_amdgcn_cvt_pk_f32_fp8((int)u, true);
    return make_float4(lo.x, lo.y, hi.x, hi.y);
#else
    unsigned int e01 = (u & 0xffu) | ((u & 0xff00u) << 8);
    unsigned int e23 = ((u >> 16) & 0xffu) | ((u & 0xff000000u) >> 8);
    unsigned int h01 = ((e01 & 0x00800080u) << 8) | (((e01 & 0x007f007fu) << 7) + 0x20002000u);
    unsigned int h23 = ((e23 & 0x00800080u) << 8) | (((e23 & 0x007f007fu) << 7) + 0x20002000u);
    union { unsigned int i; __half2 h; } t0, t1;
    t0.i = h01; t1.i = h23;
    float2 f0 = __half22float2(t0.h), f1 = __half22float2(t1.h);
    return make_float4(f0.x, f0.y, f1.x, f1.y);
#endif
}
__device__ __forceinline__ float2 fp8x2_dec(unsigned int u) {
#if __has_builtin(__builtin_amdgcn_cvt_pk_f32_fp8)
    f32x2 lo = __builtin_amdgcn_cvt_pk_f32_fp8((int)u, false);
    return make_float2(lo.x, lo.y);
#else
    unsigned int e01 = (u & 0xffu) | ((u & 0xff00u) << 8);
    unsigned int h01 = ((e01 & 0x00800080u) << 8) | (((e01 & 0x007f007fu) << 7) + 0x20002000u);
    union { unsigned int i; __half2 h; } t0;
    t0.i = h01;
    float2 f0 = __half22float2(t0.h);
    return f0;
#endif
}

// scatter-transpose 16 fp16 (from two uint4) into column nl of LDS tile
__device__ __forceinline__ void store_t16(unsigned short* dst, int c0, int nl,
                                          uint4 u0, uint4 u1) {
    unsigned int w[8] = {u0.x, u0.y, u0.z, u0.w, u1.x, u1.y, u1.z, u1.w};
#pragma unroll
    for (int i = 0; i < 8; ++i) {
        dst[(c0 + 2 * i) * LR + nl]     = (unsigned short)(w[i] & 0xffffu);
        dst[(c0 + 2 * i + 1) * LR + nl] = (unsigned short)(w[i] >> 16);
    }
}

// ---------------------------------------------------------------------------
// W transpose: wt[col][k] = W[k][col], fp16.
// ---------------------------------------------------------------------------
__global__ __launch_bounds__(128) void transpose_w(
    const float* __restrict__ Wp, const float* __restrict__ We,
    __half* __restrict__ wt)
{
    int col = blockIdx.x;
    int k   = threadIdx.x;
    float v = (col < KC) ? Wp[(size_t)k * KC + col]
                         : We[(size_t)k * KC + (col - KC)];
    wt[(size_t)col * F_IN + k] = __float2half_rn(v);
}

// ---------------------------------------------------------------------------
// K1: XW = x @ [W_pool | W_embed] -> fp8 [N,256], via MFMA 16x16x32_f16.
// ---------------------------------------------------------------------------
__global__ __launch_bounds__(256) void gemm_xw_mfma(
    const float* __restrict__ x, const __half* __restrict__ wt,
    unsigned char* __restrict__ xw8, int n_nodes)
{
    __shared__ _Float16 xs[32][136];
    const int r0 = blockIdx.x * 32;
    const int tid = threadIdx.x;
    {
        int r = tid >> 3, c0 = (tid & 7) * 16;
        int gr = r0 + r;
        if (gr < n_nodes) {
            const float4* src = (const float4*)(x + (size_t)gr * F_IN + c0);
#pragma unroll
            for (int i = 0; i < 4; ++i) {
                float4 f = src[i];
                xs[r][c0 + 4 * i + 0] = (_Float16)f.x;
                xs[r][c0 + 4 * i + 1] = (_Float16)f.y;
                xs[r][c0 + 4 * i + 2] = (_Float16)f.z;
                xs[r][c0 + 4 * i + 3] = (_Float16)f.w;
            }
        } else {
#pragma unroll
            for (int i = 0; i < 16; ++i) xs[r][c0 + i] = (_Float16)0.f;
        }
    }
    __syncthreads();

    const int w = tid >> 6, lane = tid & 63;
    const int lrow = lane & 15;
    const int lk   = (lane >> 4) * 8;

    f16x8 bfrag[4][4];
#pragma unroll
    for (int cb = 0; cb < 4; ++cb) {
        int gcol = (w * 4 + cb) * 16 + lrow;
        const f16x8* bp = (const f16x8*)(wt + (size_t)gcol * F_IN + lk);
#pragma unroll
        for (int kc = 0; kc < 4; ++kc) bfrag[cb][kc] = bp[kc * 4];
    }

    f32x4 acc[2][4];
#pragma unroll
    for (int rb = 0; rb < 2; ++rb)
#pragma unroll
        for (int cb = 0; cb < 4; ++cb) acc[rb][cb] = (f32x4){0.f, 0.f, 0.f, 0.f};

#pragma unroll
    for (int kc = 0; kc < 4; ++kc) {
        f16x8 a0 = *(const f16x8*)(&xs[lrow][kc * 32 + lk]);
        f16x8 a1 = *(const f16x8*)(&xs[16 + lrow][kc * 32 + lk]);
#pragma unroll
        for (int cb = 0; cb < 4; ++cb) {
            acc[0][cb] = __builtin_amdgcn_mfma_f32_16x16x32_f16(a0, bfrag[cb][kc], acc[0][cb], 0, 0, 0);
            acc[1][cb] = __builtin_amdgcn_mfma_f32_16x16x32_f16(a1, bfrag[cb][kc], acc[1][cb], 0, 0, 0);
        }
    }

#pragma unroll
    for (int rb = 0; rb < 2; ++rb) {
#pragma unroll
        for (int cb = 0; cb < 4; ++cb) {
            int gcol = (w * 4 + cb) * 16 + lrow;
#pragma unroll
            for (int reg = 0; reg < 4; ++reg) {
                int grow = r0 + rb * 16 + (lane >> 4) * 4 + reg;
                if (grow < n_nodes)
                    xw8[(size_t)grow * F2 + gcol] = f32_to_fp8(acc[rb][cb][reg]);
            }
        }
    }
}

// ---------------------------------------------------------------------------
// Two-level counting sort (row bins of 128), no global cursors.
// ---------------------------------------------------------------------------
__global__ __launch_bounds__(256) void bin_count(
    const int* __restrict__ erow, int* __restrict__ Cmat,
    int n_edges, int nbin, int epb)
{
    __shared__ int bc[MAXBIN];
    const int tid = threadIdx.x, blk = blockIdx.x;
    for (int i = tid; i < nbin; i += 256) bc[i] = 0;
    __syncthreads();
    int e0 = blk * epb;
    int e1 = min(e0 + epb, n_edges);
    for (int e = e0 + tid; e < e1; e += 256)
        atomicAdd(&bc[erow[e] >> BIN_SHIFT], 1);
    __syncthreads();
    for (int i = tid; i < nbin; i += 256)
        Cmat[i * NBLK_SORT + blk] = bc[i];
}

__global__ __launch_bounds__(1024) void scan_local(
    int* __restrict__ cnt, int* __restrict__ row_start,
    int* __restrict__ chunk_sum, int n)
{
    __shared__ int wsum[16];
    const int tid = threadIdx.x;
    const int lane = tid & 63, wid = tid >> 6;
    int i = blockIdx.x * 1024 + tid;
    int v = (i < n) ? cnt[i] : 0;
    int incl = v;
#pragma unroll
    for (int off = 1; off < 64; off <<= 1) {
        int t = __shfl_up(incl, off);
        if (lane >= off) incl += t;
    }
    if (lane == 63) wsum[wid] = incl;
    __syncthreads();
    if (tid == 0) {
        int s = 0;
#pragma unroll
        for (int w = 0; w < 16; ++w) { int t = wsum[w]; wsum[w] = s; s += t; }
    }
    __syncthreads();
    if (i < n) row_start[i] = wsum[wid] + incl - v;
    if (tid == 1023) chunk_sum[blockIdx.x] = wsum[15] + incl;
}

__global__ __launch_bounds__(1024) void scan_chunks(
    const int* __restrict__ chunk_sum, int* __restrict__ chunk_base,
    int* __restrict__ row_start, int nchunks, int n)
{
    __shared__ int wsum[16];
    const int tid = threadIdx.x;
    const int lane = tid & 63, wid = tid >> 6;
    int v = (tid < nchunks) ? chunk_sum[tid] : 0;
    int incl = v;
#pragma unroll
    for (int off = 1; off < 64; off <<= 1) {
        int t = __shfl_up(incl, off);
        if (lane >= off) incl += t;
    }
    if (lane == 63) wsum[wid] = incl;
    __syncthreads();
    if (tid == 0) {
        int s = 0;
#pragma unroll
        for (int w = 0; w < 16; ++w) { int t = wsum[w]; wsum[w] = s; s += t; }
    }
    __syncthreads();
    int excl = wsum[wid] + incl - v;
    if (tid < nchunks) chunk_base[tid] = excl;
    if (tid == nchunks - 1) row_start[n] = excl + v;
}

__global__ __launch_bounds__(256) void scan_add(
    int* __restrict__ row_start, const int* __restrict__ chunk_base, int n)
{
    int i = blockIdx.x * 256 + threadIdx.x;
    if (i < n) row_start[i] += chunk_base[i >> 10];
}

__global__ __launch_bounds__(256) void bin_place(
    const int* __restrict__ erow, const int* __restrict__ ecol,
    const float* __restrict__ eval_, const int* __restrict__ Coff,
    unsigned int* __restrict__ ebin_cv, unsigned char* __restrict__ ebin_r8,
    int n_edges, int nbin, int epb)
{
    __shared__ int curs[MAXBIN];
    const int tid = threadIdx.x, blk = blockIdx.x;
    for (int i = tid; i < nbin; i += 256) curs[i] = Coff[i * NBLK_SORT + blk];
    __syncthreads();
    int e0 = blk * epb;
    int e1 = min(e0 + epb, n_edges);
    for (int e = e0 + tid; e < e1; e += 256) {
        int r = erow[e];
        int b = r >> BIN_SHIFT;
        int pos = atomicAdd(&curs[b], 1);
        union { __half h; unsigned short u; } hv;
        hv.h = __float2half_rn(eval_[e]);
        ebin_cv[pos] = ((unsigned int)ecol[e] << 16) | (unsigned int)hv.u;
        ebin_r8[pos] = (unsigned char)(r & ((1 << BIN_SHIFT) - 1));
    }
}

// Pass D: one block per bin. Hist by (row, col-segment) -> local scan ->
// row_start; place into CSR slots so each row's edges are ordered by col
// segment (2 MB xw8 window per segment -> L2-resident phase-coherent gather).
__global__ __launch_bounds__(256) void bin_final(
    const unsigned int* __restrict__ ebin_cv, const unsigned char* __restrict__ ebin_r8,
    const int* __restrict__ Coff, unsigned int* __restrict__ epack,
    int* __restrict__ row_start, int n_nodes, int nbin)
{
    constexpr int RPB = 1 << BIN_SHIFT;
    constexpr int NKEY = RPB << SEG_BITS;     // 1024
    __shared__ int rcnt[NKEY];
    __shared__ int rbase[NKEY];
    const int bin = blockIdx.x, tid = threadIdx.x;
    const int beg = Coff[(size_t)bin * NBLK_SORT];
    const int end = Coff[(size_t)(bin + 1) * NBLK_SORT];
    for (int i = tid; i < NKEY; i += 256) rcnt[i] = 0;
    __syncthreads();
    for (int j = beg + tid; j < end; j += 256) {
        int key = ((int)ebin_r8[j] << SEG_BITS) | (int)(ebin_cv[j] >> (32 - SEG_BITS));
        atomicAdd(&rcnt[key], 1);
    }
    __syncthreads();
    if (tid == 0) {
        int s = 0;
        for (int i = 0; i < NKEY; ++i) { rbase[i] = s; s += rcnt[i]; }
    }
    __syncthreads();
    int grow = bin * RPB + tid;
    if (tid < RPB && grow < n_nodes)
        row_start[grow] = beg + rbase[tid << SEG_BITS];
    if (bin == nbin - 1 && tid == 0) row_start[n_nodes] = end;
    for (int i = tid; i < NKEY; i += 256) rcnt[i] = 0;
    __syncthreads();
    for (int j = beg + tid; j < end; j += 256) {
        unsigned int cv = ebin_cv[j];
        int key = ((int)ebin_r8[j] << SEG_BITS) | (int)(cv >> (32 - SEG_BITS));
        int rank = atomicAdd(&rcnt[key], 1);
        epack[beg + rbase[key] + rank] = cv;
    }
}

// ---------------------------------------------------------------------------
// K2: CSR SpMM over 256 fp8 cols, one wave/row, fused relu+softmax.
// Outputs: pqh fp16 [N,256] (S|Z) and s8 fp8 [N,128] = fp8(256*S).
// ---------------------------------------------------------------------------
__global__ __launch_bounds__(256) void spmm_dual_csr(
    const int* __restrict__ row_start, const unsigned int* __restrict__ epack,
    const unsigned char* __restrict__ xw8, __half* __restrict__ pqh,
    unsigned char* __restrict__ s8, int n_nodes)
{
    int row = blockIdx.x * 4 + (threadIdx.x >> 6);
    if (row >= n_nodes) return;
    int lane = threadIdx.x & 63;
    int beg = row_start[row], end = row_start[row + 1];

    float4 a0 = {0,0,0,0}, a1 = {0,0,0,0}, a2 = {0,0,0,0}, a3 = {0,0,0,0};
    int j = beg;
    for (; j + 3 < end; j += 4) {
        unsigned int p0 = epack[j],     p1 = epack[j + 1];
        unsigned int p2 = epack[j + 2], p3 = epack[j + 3];
        unsigned int u0 = ((const unsigned int*)(xw8 + (size_t)(p0 >> 16) * F2))[lane];
        unsigned int u1 = ((const unsigned int*)(xw8 + (size_t)(p1 >> 16) * F2))[lane];
        unsigned int u2 = ((const unsigned int*)(xw8 + (size_t)(p2 >> 16) * F2))[lane];
        unsigned int u3 = ((const unsigned int*)(xw8 + (size_t)(p3 >> 16) * F2))[lane];
        float v0 = pe_val(p0), v1 = pe_val(p1), v2 = pe_val(p2), v3 = pe_val(p3);
        float4 s0 = fp8x4_dec(u0), s1 = fp8x4_dec(u1);
        float4 s2 = fp8x4_dec(u2), s3 = fp8x4_dec(u3);
        a0.x += v0 * s0.x; a0.y += v0 * s0.y; a0.z += v0 * s0.z; a0.w += v0 * s0.w;
        a1.x += v1 * s1.x; a1.y += v1 * s1.y; a1.z += v1 * s1.z; a1.w += v1 * s1.w;
        a2.x += v2 * s2.x; a2.y += v2 * s2.y; a2.z += v2 * s2.z; a2.w += v2 * s2.w;
        a3.x += v3 * s3.x; a3.y += v3 * s3.y; a3.z += v3 * s3.z; a3.w += v3 * s3.w;
    }
    for (; j < end; ++j) {
        unsigned int p = epack[j];
        unsigned int u = ((const unsigned int*)(xw8 + (size_t)(p >> 16) * F2))[lane];
        float v = pe_val(p);
        float4 s = fp8x4_dec(u);
        a0.x += v * s.x; a0.y += v * s.y; a0.z += v * s.z; a0.w += v * s.w;
    }
    float4 a;
    a.x = a0.x + a1.x + a2.x + a3.x;
    a.y = a0.y + a1.y + a2.y + a3.y;
    a.z = a0.z + a1.z + a2.z + a3.z;
    a.w = a0.w + a1.w + a2.w + a3.w;

    a.x = fmaxf(a.x, 0.f); a.y = fmaxf(a.y, 0.f);
    a.z = fmaxf(a.z, 0.f); a.w = fmaxf(a.w, 0.f);

    float m = fmaxf(fmaxf(a.x, a.y), fmaxf(a.z, a.w));
#pragma unroll
    for (int off = 16; off; off >>= 1) m = fmaxf(m, __shfl_xor(m, off));
    float ex = __expf(a.x - m), ey = __expf(a.y - m);
    float ez = __expf(a.z - m), ew = __expf(a.w - m);
    float ssum = ex + ey + ez + ew;
#pragma unroll
    for (int off = 16; off; off >>= 1) ssum += __shfl_xor(ssum, off);
    float inv = 1.f / ssum;

    bool isP = lane < 32;
    float wx = isP ? ex * inv : a.x;
    float wy = isP ? ey * inv : a.y;
    float wz = isP ? ez * inv : a.z;
    float ww = isP ? ew * inv : a.w;
    ((uint2*)(pqh + (size_t)row * F2))[lane] =
        make_uint2(f2_to_h2u(wx, wy), f2_to_h2u(wz, ww));
    if (isP) {
        unsigned int pk = (unsigned int)f32_to_fp8(wx * 256.f)
                        | ((unsigned int)f32_to_fp8(wy * 256.f) << 8)
                        | ((unsigned int)f32_to_fp8(wz * 256.f) << 16)
                        | ((unsigned int)f32_to_fp8(ww * 256.f) << 24);
        ((unsigned int*)(s8 + (size_t)row * KC))[lane] = pk;
    }
}

// ---------------------------------------------------------------------------
// K4: AS = A @ S via fp8 gather of s8 (=256*S); 1/256 folded into edge val.
// ---------------------------------------------------------------------------
__global__ __launch_bounds__(256) void spmm_s_csr(
    const int* __restrict__ row_start, const unsigned int* __restrict__ epack,
    const unsigned char* __restrict__ s8, __half* __restrict__ ash, int n_nodes)
{
    int row = blockIdx.x * 4 + (threadIdx.x >> 6);
    if (row >= n_nodes) return;
    int lane = threadIdx.x & 63;
    int beg = row_start[row], end = row_start[row + 1];

    float2 a0 = {0,0}, a1 = {0,0}, a2 = {0,0}, a3 = {0,0};
    int j = beg;
    for (; j + 3 < end; j += 4) {
        unsigned int p0 = epack[j],     p1 = epack[j + 1];
        unsigned int p2 = epack[j + 2], p3 = epack[j + 3];
        unsigned int u0 = ((const unsigned short*)(s8 + (size_t)(p0 >> 16) * KC))[lane];
        unsigned int u1 = ((const unsigned short*)(s8 + (size_t)(p1 >> 16) * KC))[lane];
        unsigned int u2 = ((const unsigned short*)(s8 + (size_t)(p2 >> 16) * KC))[lane];
        unsigned int u3 = ((const unsigned short*)(s8 + (size_t)(p3 >> 16) * KC))[lane];
        float v0 = pe_val(p0) * (1.f / 256.f), v1 = pe_val(p1) * (1.f / 256.f);
        float v2 = pe_val(p2) * (1.f / 256.f), v3 = pe_val(p3) * (1.f / 256.f);
        float2 f0 = fp8x2_dec(u0), f1 = fp8x2_dec(u1);
        float2 f2 = fp8x2_dec(u2), f3 = fp8x2_dec(u3);
        a0.x += v0 * f0.x; a0.y += v0 * f0.y;
        a1.x += v1 * f1.x; a1.y += v1 * f1.y;
        a2.x += v2 * f2.x; a2.y += v2 * f2.y;
        a3.x += v3 * f3.x; a3.y += v3 * f3.y;
    }
    for (; j < end; ++j) {
        unsigned int p = epack[j];
        unsigned int u = ((const unsigned short*)(s8 + (size_t)(p >> 16) * KC))[lane];
        float v = pe_val(p) * (1.f / 256.f);
        float2 f = fp8x2_dec(u);
        a0.x += v * f.x; a0.y += v * f.y;
    }
    float rx = a0.x + a1.x + a2.x + a3.x;
    float ry = a0.y + a1.y + a2.y + a3.y;
    union { __half2 h; unsigned int i; } o;
    o.h = __floats2half2_rn(rx, ry);
    ((unsigned int*)(ash + (size_t)row * KC))[lane] = o.i;
}

// ---------------------------------------------------------------------------
// K5a: coarse partials via MFMA. which = blockIdx.y (0: S^T@AS, 1: S^T@Z).
// ---------------------------------------------------------------------------
__global__ __launch_bounds__(256) void coarse_part_mfma(
    const __half* __restrict__ pqh, const __half* __restrict__ ash,
    float* __restrict__ part, int n_nodes)
{
    __shared__ _Float16 sSt[128 * LR];   // S^T: [cluster m][node k]
    __shared__ _Float16 sVt[128 * LR];   // V^T: [feat f][node k]
    const int which = blockIdx.y;
    const int tid = threadIdx.x;
    const int w = tid >> 6, lane = tid & 63;
    const int nl = tid & 31;
    const int c0 = (tid >> 5) * 16;
    const int fr = lane & 15;
    const int fk = (lane >> 4) * 8;

    f32x4 acc[2][8];
#pragma unroll
    for (int b = 0; b < 2; ++b)
#pragma unroll
        for (int fb = 0; fb < 8; ++fb) acc[b][fb] = (f32x4){0.f, 0.f, 0.f, 0.f};

    const int stride = gridDim.x * 32;
    for (int n0 = blockIdx.x * 32; n0 < n_nodes; n0 += stride) {
        __syncthreads();
        int n = n0 + nl;
        if (n < n_nodes) {
            uint4 u0 = *(const uint4*)(pqh + (size_t)n * F2 + c0);
            uint4 u1 = *(const uint4*)(pqh + (size_t)n * F2 + c0 + 8);
            store_t16((unsigned short*)sSt, c0, nl, u0, u1);
            uint4 v0, v1;
            if (which) {
                v0 = *(const uint4*)(pqh + (size_t)n * F2 + KC + c0);
                v1 = *(const uint4*)(pqh + (size_t)n * F2 + KC + c0 + 8);
            } else {
                v0 = *(const uint4*)(ash + (size_t)n * KC + c0);
                v1 = *(const uint4*)(ash + (size_t)n * KC + c0 + 8);
            }
            store_t16((unsigned short*)sVt, c0, nl, v0, v1);
        } else {
#pragma unroll
            for (int i = 0; i < 16; ++i) {
                sSt[(c0 + i) * LR + nl] = (_Float16)0.f;
                sVt[(c0 + i) * LR + nl] = (_Float16)0.f;
            }
        }
        __syncthreads();

        f16x8 a0 = *(const f16x8*)(&sSt[((2 * w + 0) * 16 + fr) * LR + fk]);
        f16x8 a1 = *(const f16x8*)(&sSt[((2 * w + 1) * 16 + fr) * LR + fk]);
#pragma unroll
        for (int fb = 0; fb < 8; ++fb) {
            f16x8 bf = *(const f16x8*)(&sVt[(fb * 16 + fr) * LR + fk]);
            acc[0][fb] = __builtin_amdgcn_mfma_f32_16x16x32_f16(a0, bf, acc[0][fb], 0, 0, 0);
            acc[1][fb] = __builtin_amdgcn_mfma_f32_16x16x32_f16(a1, bf, acc[1][fb], 0, 0, 0);
        }
    }

    float* p = part + ((size_t)which * gridDim.x + blockIdx.x) * (KC * KC);
#pragma unroll
    for (int b = 0; b < 2; ++b) {
        int mbase = (2 * w + b) * 16 + (lane >> 4) * 4;
#pragma unroll
        for (int fb = 0; fb < 8; ++fb) {
            int f = fb * 16 + fr;
#pragma unroll
            for (int reg = 0; reg < 4; ++reg)
                p[(size_t)(mbase + reg) * KC + f] = acc[b][fb][reg];
        }
    }
}

// K5b stage 1: part2[s][e] = sum of this split's tiles (grid: 128 x NSPLIT)
__global__ __launch_bounds__(256) void coarse_reduce1(
    const float* __restrict__ part, float* __restrict__ part2, int nb)
{
    int e = blockIdx.x * 256 + threadIdx.x;
    int s = blockIdx.y;
    int which = e >> 14;
    int idx = e & 16383;
    int tpb = nb / NSPLIT;
    const float* p = part + ((size_t)which * nb + (size_t)s * tpb) * (KC * KC) + idx;
    float sum = 0.f;
    for (int t = 0; t < tpb; ++t) sum += p[(size_t)t * (KC * KC)];
    part2[(size_t)s * (2 * KC * KC) + e] = sum;
}

// K5b stage 2: out[e] = sum over NSPLIT partials (full overwrite of d_out)
__global__ __launch_bounds__(256) void coarse_reduce2(
    const float* __restrict__ part2, float* __restrict__ out)
{
    int e = blockIdx.x * 256 + threadIdx.x;
    float s = 0.f;
#pragma unroll
    for (int i = 0; i < NSPLIT; ++i) s += part2[(size_t)i * (2 * KC * KC) + e];
    out[e] = s;
}

// ---------------------------------------------------------------------------
// Fallback f32 atomic path
// ---------------------------------------------------------------------------
__global__ __launch_bounds__(256) void gemm_xw_f(
    const float* __restrict__ x, const float* __restrict__ Wp,
    const float* __restrict__ We, float* __restrict__ xw, int n_nodes)
{
    constexpr int RPB = 32;
    __shared__ float xs[RPB][F_IN];
    const int r0 = blockIdx.x * RPB;
    const int tid = threadIdx.x;
    for (int i = tid; i < RPB * F_IN; i += 256) {
        int r = i >> 7, c = i & 127;
        int gr = r0 + r;
        xs[r][c] = (gr < n_nodes) ? x[(size_t)gr * F_IN + c] : 0.f;
    }
    __syncthreads();
    const int col = tid;
    const float* W = (col < KC) ? (Wp + col) : (We + (col - KC));
    float acc[RPB];
#pragma unroll
    for (int r = 0; r < RPB; ++r) acc[r] = 0.f;
    for (int k = 0; k < F_IN; ++k) {
        float w = W[(size_t)k * KC];
        const float* xk = &xs[0][k];
#pragma unroll
        for (int r = 0; r < RPB; ++r) acc[r] += xk[r * F_IN] * w;
    }
#pragma unroll
    for (int r = 0; r < RPB; ++r) {
        int gr = r0 + r;
        if (gr < n_nodes) xw[(size_t)gr * F2 + col] = acc[r];
    }
}

__global__ __launch_bounds__(256) void spmm_dual_kernel(
    const int* __restrict__ erow, const int* __restrict__ ecol,
    const float* __restrict__ eval_, const float* __restrict__ xw,
    float* __restrict__ pq, int n_edges)
{
    int e = blockIdx.x * 4 + (threadIdx.x >> 6);
    if (e >= n_edges) return;
    int lane = threadIdx.x & 63;
    int r = erow[e], c = ecol[e];
    float v = eval_[e];
    const float4* src = (const float4*)(xw + (size_t)c * F2);
    float* dst = pq + (size_t)r * F2;
    float4 s = src[lane];
    int f = lane * 4;
    atomicAdd(&dst[f + 0], v * s.x);
    atomicAdd(&dst[f + 1], v * s.y);
    atomicAdd(&dst[f + 2], v * s.z);
    atomicAdd(&dst[f + 3], v * s.w);
}

__global__ __launch_bounds__(64) void softmax_relu_kernel(
    float* __restrict__ pq, int n_nodes)
{
    int n = blockIdx.x;
    if (n >= n_nodes) return;
    int lane = threadIdx.x;
    float* p = pq + (size_t)n * F2;
    float a0 = fmaxf(p[lane], 0.f);
    float a1 = fmaxf(p[lane + 64], 0.f);
    float m = fmaxf(a0, a1);
#pragma unroll
    for (int off = 32; off; off >>= 1) m = fmaxf(m, __shfl_xor(m, off));
    float e0 = __expf(a0 - m), e1 = __expf(a1 - m);
    float ssum = e0 + e1;
#pragma unroll
    for (int off = 32; off; off >>= 1) ssum += __shfl_xor(ssum, off);
    float inv = 1.f / ssum;
    p[lane]      = e0 * inv;
    p[lane + 64] = e1 * inv;
    p[lane + 128] = fmaxf(p[lane + 128], 0.f);
    p[lane + 192] = fmaxf(p[lane + 192], 0.f);
}

__global__ __launch_bounds__(256) void spmm_s_kernel(
    const int* __restrict__ erow, const int* __restrict__ ecol,
    const float* __restrict__ eval_, const float* __restrict__ pq,
    float* __restrict__ as_, int n_edges)
{
    int e = blockIdx.x * 4 + (threadIdx.x >> 6);
    if (e >= n_edges) return;
    int lane = threadIdx.x & 63;
    int r = erow[e], c = ecol[e];
    float v = eval_[e];
    const float2* src = (const float2*)(pq + (size_t)c * F2);
    float* dst = as_ + (size_t)r * KC;
    float2 s = src[lane];
    int f = lane * 2;
    atomicAdd(&dst[f + 0], v * s.x);
    atomicAdd(&dst[f + 1], v * s.y);
}

__global__ __launch_bounds__(256) void coarse_f(
    const float* __restrict__ pq, const float* __restrict__ as_,
    float* __restrict__ out, int n_nodes)
{
    const int which = blockIdx.y;
    const int tid = threadIdx.x;
    const int f  = tid & 127;
    const int k0 = (tid >> 7) * 64;
    __shared__ float sS[8][128];
    float acc[64];
#pragma unroll
    for (int i = 0; i < 64; ++i) acc[i] = 0.f;
    const int stride = gridDim.x * 8;
    for (int n0 = blockIdx.x * 8; n0 < n_nodes; n0 += stride) {
        __syncthreads();
        for (int i = tid; i < 8 * 128; i += 256) {
            int rr = i >> 7, cc = i & 127;
            int n = n0 + rr;
            sS[rr][cc] = (n < n_nodes) ? pq[(size_t)n * F2 + cc] : 0.f;
        }
        __syncthreads();
        int rmax = (n_nodes - n0 < 8) ? (n_nodes - n0) : 8;
        for (int rr = 0; rr < rmax; ++rr) {
            int n = n0 + rr;
            float v = which ? pq[(size_t)n * F2 + KC + f]
                            : as_[(size_t)n * KC + f];
            const float4* s4 = (const float4*)(&sS[rr][k0]);
#pragma unroll
            for (int i = 0; i < 16; ++i) {
                float4 sv = s4[i];
                acc[4 * i + 0] += sv.x * v;
                acc[4 * i + 1] += sv.y * v;
                acc[4 * i + 2] += sv.z * v;
                acc[4 * i + 3] += sv.w * v;
            }
        }
    }
    float* o = out + (size_t)which * (KC * KC);
#pragma unroll
    for (int i = 0; i < 64; ++i)
        atomicAdd(&o[(size_t)(k0 + i) * KC + f], acc[i]);
}

// ---------------------------------------------------------------------------
extern "C" void kernel_launch(void* const* d_in, const int* in_sizes, int n_in,
                              void* d_out, int out_size, void* d_ws, size_t ws_size,
                              hipStream_t stream)
{
    const float* x     = (const float*)d_in[0];
    const int*   erow  = (const int*)d_in[1];
    const int*   ecol  = (const int*)d_in[2];
    const float* eval_ = (const float*)d_in[3];
    const float* Wp    = (const float*)d_in[4];
    const float* We    = (const float*)d_in[5];
    float* out = (float*)d_out;

    const int n_nodes = in_sizes[0] / F_IN;
    const int n_edges = in_sizes[1];
    const int nbin = (n_nodes + (1 << BIN_SHIFT) - 1) >> BIN_SHIFT;
    const int M = nbin * NBLK_SORT;
    const int mchunks = (M + 1023) / 1024;
    const int epb = (n_edges + NBLK_SORT - 1) / NBLK_SORT;

    char* base = (char*)d_ws;
    size_t off = 0;
    auto alloc = [&](size_t bytes) -> void* {
        off = (off + 255) & ~(size_t)255;
        void* p = base + off;
        off += bytes;
        return p;
    };
    unsigned char* xw8  = (unsigned char*)alloc((size_t)n_nodes * F2);
    __half* pqh         = (__half*)alloc((size_t)n_nodes * F2 * 2);
    __half* ash         = (__half*)alloc((size_t)n_nodes * KC * 2);
    unsigned char* s8   = (unsigned char*)alloc((size_t)n_nodes * KC);
    int* row_start      = (int*)alloc(((size_t)n_nodes + 1) * 4);
    unsigned int* epack = (unsigned int*)alloc((size_t)n_edges * 4);
    unsigned int* ebin_cv = (unsigned int*)alloc((size_t)n_edges * 4);
    unsigned char* ebin_r8 = (unsigned char*)alloc((size_t)n_edges);
    int* Cmat           = (int*)alloc((size_t)M * 4);
    int* Coff           = (int*)alloc(((size_t)M + 1) * 4);
    int* chunk_sum      = (int*)alloc(1024 * 4);
    int* chunk_base     = (int*)alloc(1024 * 4);
    __half* wt          = (__half*)alloc((size_t)F2 * F_IN * 2);
    float* part         = (float*)alloc((size_t)2 * NB_COARSE * KC * KC * 4);
    float* part2        = (float*)alloc((size_t)NSPLIT * 2 * KC * KC * 4);
    const size_t needed_h = off;

    if (n_nodes <= 65535 && nbin <= MAXBIN && mchunks <= 1024 && ws_size >= needed_h) {
        // ---- fast fp8/fp16 counting-sort + MFMA path ----
        transpose_w<<<F2, 128, 0, stream>>>(Wp, We, wt);
        gemm_xw_mfma<<<(n_nodes + 31) / 32, 256, 0, stream>>>(x, wt, xw8, n_nodes);

        bin_count<<<NBLK_SORT, 256, 0, stream>>>(erow, Cmat, n_edges, nbin, epb);
        scan_local<<<mchunks, 1024, 0, stream>>>(Cmat, Coff, chunk_sum, M);
        scan_chunks<<<1, 1024, 0, stream>>>(chunk_sum, chunk_base, Coff, mchunks, M);
        scan_add<<<(M + 255) / 256, 256, 0, stream>>>(Coff, chunk_base, M);
        bin_place<<<NBLK_SORT, 256, 0, stream>>>(erow, ecol, eval_, Coff,
                                                 ebin_cv, ebin_r8, n_edges, nbin, epb);
        bin_final<<<nbin, 256, 0, stream>>>(ebin_cv, ebin_r8, Coff, epack,
                                            row_start, n_nodes, nbin);

        spmm_dual_csr<<<(n_nodes + 3) / 4, 256, 0, stream>>>(
            row_start, epack, xw8, pqh, s8, n_nodes);
        spmm_s_csr<<<(n_nodes + 3) / 4, 256, 0, stream>>>(
            row_start, epack, s8, ash, n_nodes);

        coarse_part_mfma<<<dim3(NB_COARSE, 2), 256, 0, stream>>>(pqh, ash, part, n_nodes);
        coarse_reduce1<<<dim3((2 * KC * KC) / 256, NSPLIT), 256, 0, stream>>>(
            part, part2, NB_COARSE);
        coarse_reduce2<<<(2 * KC * KC) / 256, 256, 0, stream>>>(part2, out);
    } else {
        // ---- f32 atomic fallback ----
        float* xw  = (float*)d_ws;
        float* pq  = xw + (size_t)n_nodes * F2;
        float* as_ = xw;
        hipMemsetAsync(d_out, 0, (size_t)out_size * sizeof(float), stream);
        gemm_xw_f<<<(n_nodes + 31) / 32, 256, 0, stream>>>(x, Wp, We, xw, n_nodes);
        hipMemsetAsync(pq, 0, (size_t)n_nodes * F2 * sizeof(float), stream);
        spmm_dual_kernel<<<(n_edges + 3) / 4, 256, 0, stream>>>(
            erow, ecol, eval_, xw, pq, n_edges);
        softmax_relu_kernel<<<n_nodes, 64, 0, stream>>>(pq, n_nodes);
        hipMemsetAsync(as_, 0, (size_t)n_nodes * KC * sizeof(float), stream);
        spmm_s_kernel<<<(n_edges + 3) / 4, 256, 0, stream>>>(
            erow, ecol, eval_, pq, as_, n_edges);
        coarse_f<<<dim3(128, 2), 256, 0, stream>>>(pq, as_, out, n_nodes);
    }
}

// Round 11
// 220.775 us; speedup vs baseline: 1.0822x; 1.0822x over previous
//
#include <hip/hip_runtime.h>
#include <hip/hip_fp16.h>

constexpr int F_IN = 128;
constexpr int KC   = 128;   // K_CLUST == F_EMB == 128
constexpr int F2   = 256;   // K_CLUST + F_EMB
constexpr int NB_COARSE = 256;   // partial tiles per output
constexpr int NSPLIT = 8;        // t-axis split in coarse reduce stage 1
constexpr int NBLK_SORT = 256;   // blocks in bin-count / bin-place passes
constexpr int BIN_SHIFT = 7;     // 128 rows per bin
constexpr int MAXBIN = 512;      // ceil(65536/128)
constexpr int LR = 40;           // LDS row stride (fp16 units); 80B = 5*16B

typedef _Float16 f16x8 __attribute__((ext_vector_type(8)));
typedef float    f32x4 __attribute__((ext_vector_type(4)));
typedef float    f32x2 __attribute__((ext_vector_type(2)));

// ---------- fp16 helpers ----------
__device__ __forceinline__ unsigned int f2_to_h2u(float x, float y) {
    union { __half2 h; unsigned int i; } c;
    c.h = __floats2half2_rn(x, y);
    return c.i;
}
__device__ __forceinline__ float pe_val(unsigned int pe) {
    return __half2float(__ushort_as_half((unsigned short)(pe & 0xffffu)));
}

// ---------- fp8 e4m3fn helpers ----------
__device__ __forceinline__ unsigned char f32_to_fp8(float f) {
    union { __half h; unsigned short u; } c; c.h = __float2half_rn(f);
    unsigned short h = c.u;
    unsigned int s = (h >> 8) & 0x80u;
    int e5 = (h >> 10) & 0x1f;
    if (e5 < 9) return (unsigned char)s;
    unsigned int c7 = ((unsigned int)(e5 - 8) << 3) | ((h >> 7) & 7u);
    unsigned int rem = h & 0x7fu;
    c7 += (rem > 0x40u) || ((rem == 0x40u) && (c7 & 1u));
    if (c7 > 0x7eu) c7 = 0x7eu;
    return (unsigned char)(s | c7);
}
__device__ __forceinline__ float4 fp8x4_dec(unsigned int u) {
#if __has_builtin(__builtin_amdgcn_cvt_pk_f32_fp8)
    f32x2 lo = __builtin_amdgcn_cvt_pk_f32_fp8((int)u, false);
    f32x2 hi = __builtin_amdgcn_cvt_pk_f32_fp8((int)u, true);
    return make_float4(lo.x, lo.y, hi.x, hi.y);
#else
    unsigned int e01 = (u & 0xffu) | ((u & 0xff00u) << 8);
    unsigned int e23 = ((u >> 16) & 0xffu) | ((u & 0xff000000u) >> 8);
    unsigned int h01 = ((e01 & 0x00800080u) << 8) | (((e01 & 0x007f007fu) << 7) + 0x20002000u);
    unsigned int h23 = ((e23 & 0x00800080u) << 8) | (((e23 & 0x007f007fu) << 7) + 0x20002000u);
    union { unsigned int i; __half2 h; } t0, t1;
    t0.i = h01; t1.i = h23;
    float2 f0 = __half22float2(t0.h), f1 = __half22float2(t1.h);
    return make_float4(f0.x, f0.y, f1.x, f1.y);
#endif
}
__device__ __forceinline__ float2 fp8x2_dec(unsigned int u) {
#if __has_builtin(__builtin_amdgcn_cvt_pk_f32_fp8)
    f32x2 lo = __builtin_amdgcn_cvt_pk_f32_fp8((int)u, false);
    return make_float2(lo.x, lo.y);
#else
    unsigned int e01 = (u & 0xffu) | ((u & 0xff00u) << 8);
    unsigned int h01 = ((e01 & 0x00800080u) << 8) | (((e01 & 0x007f007fu) << 7) + 0x20002000u);
    union { unsigned int i; __half2 h; } t0;
    t0.i = h01;
    float2 f0 = __half22float2(t0.h);
    return f0;
#endif
}

// scatter-transpose 16 fp16 (from two uint4) into column nl of LDS tile
__device__ __forceinline__ void store_t16(unsigned short* dst, int c0, int nl,
                                          uint4 u0, uint4 u1) {
    unsigned int w[8] = {u0.x, u0.y, u0.z, u0.w, u1.x, u1.y, u1.z, u1.w};
#pragma unroll
    for (int i = 0; i < 8; ++i) {
        dst[(c0 + 2 * i) * LR + nl]     = (unsigned short)(w[i] & 0xffffu);
        dst[(c0 + 2 * i + 1) * LR + nl] = (unsigned short)(w[i] >> 16);
    }
}

// ---------------------------------------------------------------------------
// W transpose: wt[col][k] = W[k][col], fp16.
// ---------------------------------------------------------------------------
__global__ __launch_bounds__(128) void transpose_w(
    const float* __restrict__ Wp, const float* __restrict__ We,
    __half* __restrict__ wt)
{
    int col = blockIdx.x;
    int k   = threadIdx.x;
    float v = (col < KC) ? Wp[(size_t)k * KC + col]
                         : We[(size_t)k * KC + (col - KC)];
    wt[(size_t)col * F_IN + k] = __float2half_rn(v);
}

// ---------------------------------------------------------------------------
// K1: XW = x @ [W_pool | W_embed] -> fp8 [N,256], via MFMA 16x16x32_f16.
// ---------------------------------------------------------------------------
__global__ __launch_bounds__(256) void gemm_xw_mfma(
    const float* __restrict__ x, const __half* __restrict__ wt,
    unsigned char* __restrict__ xw8, int n_nodes)
{
    __shared__ _Float16 xs[32][136];
    const int r0 = blockIdx.x * 32;
    const int tid = threadIdx.x;
    {
        int r = tid >> 3, c0 = (tid & 7) * 16;
        int gr = r0 + r;
        if (gr < n_nodes) {
            const float4* src = (const float4*)(x + (size_t)gr * F_IN + c0);
#pragma unroll
            for (int i = 0; i < 4; ++i) {
                float4 f = src[i];
                xs[r][c0 + 4 * i + 0] = (_Float16)f.x;
                xs[r][c0 + 4 * i + 1] = (_Float16)f.y;
                xs[r][c0 + 4 * i + 2] = (_Float16)f.z;
                xs[r][c0 + 4 * i + 3] = (_Float16)f.w;
            }
        } else {
#pragma unroll
            for (int i = 0; i < 16; ++i) xs[r][c0 + i] = (_Float16)0.f;
        }
    }
    __syncthreads();

    const int w = tid >> 6, lane = tid & 63;
    const int lrow = lane & 15;
    const int lk   = (lane >> 4) * 8;

    f16x8 bfrag[4][4];
#pragma unroll
    for (int cb = 0; cb < 4; ++cb) {
        int gcol = (w * 4 + cb) * 16 + lrow;
        const f16x8* bp = (const f16x8*)(wt + (size_t)gcol * F_IN + lk);
#pragma unroll
        for (int kc = 0; kc < 4; ++kc) bfrag[cb][kc] = bp[kc * 4];
    }

    f32x4 acc[2][4];
#pragma unroll
    for (int rb = 0; rb < 2; ++rb)
#pragma unroll
        for (int cb = 0; cb < 4; ++cb) acc[rb][cb] = (f32x4){0.f, 0.f, 0.f, 0.f};

#pragma unroll
    for (int kc = 0; kc < 4; ++kc) {
        f16x8 a0 = *(const f16x8*)(&xs[lrow][kc * 32 + lk]);
        f16x8 a1 = *(const f16x8*)(&xs[16 + lrow][kc * 32 + lk]);
#pragma unroll
        for (int cb = 0; cb < 4; ++cb) {
            acc[0][cb] = __builtin_amdgcn_mfma_f32_16x16x32_f16(a0, bfrag[cb][kc], acc[0][cb], 0, 0, 0);
            acc[1][cb] = __builtin_amdgcn_mfma_f32_16x16x32_f16(a1, bfrag[cb][kc], acc[1][cb], 0, 0, 0);
        }
    }

#pragma unroll
    for (int rb = 0; rb < 2; ++rb) {
#pragma unroll
        for (int cb = 0; cb < 4; ++cb) {
            int gcol = (w * 4 + cb) * 16 + lrow;
#pragma unroll
            for (int reg = 0; reg < 4; ++reg) {
                int grow = r0 + rb * 16 + (lane >> 4) * 4 + reg;
                if (grow < n_nodes)
                    xw8[(size_t)grow * F2 + gcol] = f32_to_fp8(acc[rb][cb][reg]);
            }
        }
    }
}

// ---------------------------------------------------------------------------
// Two-level counting sort (row bins of 128), no global cursors.
// ---------------------------------------------------------------------------
__global__ __launch_bounds__(256) void bin_count(
    const int* __restrict__ erow, int* __restrict__ Cmat,
    int n_edges, int nbin, int epb)
{
    __shared__ int bc[MAXBIN];
    const int tid = threadIdx.x, blk = blockIdx.x;
    for (int i = tid; i < nbin; i += 256) bc[i] = 0;
    __syncthreads();
    int e0 = blk * epb;
    int e1 = min(e0 + epb, n_edges);
    for (int e = e0 + tid; e < e1; e += 256)
        atomicAdd(&bc[erow[e] >> BIN_SHIFT], 1);
    __syncthreads();
    for (int i = tid; i < nbin; i += 256)
        Cmat[i * NBLK_SORT + blk] = bc[i];
}

__global__ __launch_bounds__(1024) void scan_local(
    int* __restrict__ cnt, int* __restrict__ row_start,
    int* __restrict__ chunk_sum, int n)
{
    __shared__ int wsum[16];
    const int tid = threadIdx.x;
    const int lane = tid & 63, wid = tid >> 6;
    int i = blockIdx.x * 1024 + tid;
    int v = (i < n) ? cnt[i] : 0;
    int incl = v;
#pragma unroll
    for (int off = 1; off < 64; off <<= 1) {
        int t = __shfl_up(incl, off);
        if (lane >= off) incl += t;
    }
    if (lane == 63) wsum[wid] = incl;
    __syncthreads();
    if (tid == 0) {
        int s = 0;
#pragma unroll
        for (int w = 0; w < 16; ++w) { int t = wsum[w]; wsum[w] = s; s += t; }
    }
    __syncthreads();
    if (i < n) row_start[i] = wsum[wid] + incl - v;
    if (tid == 1023) chunk_sum[blockIdx.x] = wsum[15] + incl;
}

__global__ __launch_bounds__(1024) void scan_chunks(
    const int* __restrict__ chunk_sum, int* __restrict__ chunk_base,
    int* __restrict__ row_start, int nchunks, int n)
{
    __shared__ int wsum[16];
    const int tid = threadIdx.x;
    const int lane = tid & 63, wid = tid >> 6;
    int v = (tid < nchunks) ? chunk_sum[tid] : 0;
    int incl = v;
#pragma unroll
    for (int off = 1; off < 64; off <<= 1) {
        int t = __shfl_up(incl, off);
        if (lane >= off) incl += t;
    }
    if (lane == 63) wsum[wid] = incl;
    __syncthreads();
    if (tid == 0) {
        int s = 0;
#pragma unroll
        for (int w = 0; w < 16; ++w) { int t = wsum[w]; wsum[w] = s; s += t; }
    }
    __syncthreads();
    int excl = wsum[wid] + incl - v;
    if (tid < nchunks) chunk_base[tid] = excl;
    if (tid == nchunks - 1) row_start[n] = excl + v;
}

__global__ __launch_bounds__(256) void scan_add(
    int* __restrict__ row_start, const int* __restrict__ chunk_base, int n)
{
    int i = blockIdx.x * 256 + threadIdx.x;
    if (i < n) row_start[i] += chunk_base[i >> 10];
}

__global__ __launch_bounds__(256) void bin_place(
    const int* __restrict__ erow, const int* __restrict__ ecol,
    const float* __restrict__ eval_, const int* __restrict__ Coff,
    unsigned int* __restrict__ ebin_cv, unsigned char* __restrict__ ebin_r8,
    int n_edges, int nbin, int epb)
{
    __shared__ int curs[MAXBIN];
    const int tid = threadIdx.x, blk = blockIdx.x;
    for (int i = tid; i < nbin; i += 256) curs[i] = Coff[i * NBLK_SORT + blk];
    __syncthreads();
    int e0 = blk * epb;
    int e1 = min(e0 + epb, n_edges);
    for (int e = e0 + tid; e < e1; e += 256) {
        int r = erow[e];
        int b = r >> BIN_SHIFT;
        int pos = atomicAdd(&curs[b], 1);
        union { __half h; unsigned short u; } hv;
        hv.h = __float2half_rn(eval_[e]);
        ebin_cv[pos] = ((unsigned int)ecol[e] << 16) | (unsigned int)hv.u;
        ebin_r8[pos] = (unsigned char)(r & ((1 << BIN_SHIFT) - 1));
    }
}

// Pass D (row-only key, R9 form): one block per bin. LDS row-hist -> local
// scan -> row_start; final place into exact CSR slots.
__global__ __launch_bounds__(256) void bin_final(
    const unsigned int* __restrict__ ebin_cv, const unsigned char* __restrict__ ebin_r8,
    const int* __restrict__ Coff, unsigned int* __restrict__ epack,
    int* __restrict__ row_start, int n_nodes, int nbin)
{
    constexpr int RPB = 1 << BIN_SHIFT;
    __shared__ int rcnt[RPB];
    __shared__ int rbase[RPB];
    const int bin = blockIdx.x, tid = threadIdx.x;
    const int beg = Coff[(size_t)bin * NBLK_SORT];
    const int end = Coff[(size_t)(bin + 1) * NBLK_SORT];
    if (tid < RPB) rcnt[tid] = 0;
    __syncthreads();
    for (int j = beg + tid; j < end; j += 256)
        atomicAdd(&rcnt[ebin_r8[j]], 1);
    __syncthreads();
    if (tid == 0) {
        int s = 0;
#pragma unroll
        for (int i = 0; i < RPB; ++i) { rbase[i] = s; s += rcnt[i]; }
    }
    __syncthreads();
    int grow = bin * RPB + tid;
    if (tid < RPB && grow < n_nodes) row_start[grow] = beg + rbase[tid];
    if (bin == nbin - 1 && tid == 0) row_start[n_nodes] = end;
    if (tid < RPB) rcnt[tid] = 0;
    __syncthreads();
    for (int j = beg + tid; j < end; j += 256) {
        int r8 = ebin_r8[j];
        int rank = atomicAdd(&rcnt[r8], 1);
        epack[beg + rbase[r8] + rank] = ebin_cv[j];
    }
}

// ---------------------------------------------------------------------------
// K2: CSR SpMM over 256 fp8 cols, one wave/row, fused relu+softmax.
// 8-deep gather pipeline (MLP experiment). Outputs: pqh fp16 (S|Z), s8 fp8.
// ---------------------------------------------------------------------------
__global__ __launch_bounds__(256) void spmm_dual_csr(
    const int* __restrict__ row_start, const unsigned int* __restrict__ epack,
    const unsigned char* __restrict__ xw8, __half* __restrict__ pqh,
    unsigned char* __restrict__ s8, int n_nodes)
{
    int row = blockIdx.x * 4 + (threadIdx.x >> 6);
    if (row >= n_nodes) return;
    int lane = threadIdx.x & 63;
    int beg = row_start[row], end = row_start[row + 1];

    float4 a0 = {0,0,0,0}, a1 = {0,0,0,0}, a2 = {0,0,0,0}, a3 = {0,0,0,0};
    int j = beg;
    for (; j + 7 < end; j += 8) {
        unsigned int p[8];
#pragma unroll
        for (int t = 0; t < 8; ++t) p[t] = epack[j + t];
        unsigned int u[8];
#pragma unroll
        for (int t = 0; t < 8; ++t)
            u[t] = ((const unsigned int*)(xw8 + (size_t)(p[t] >> 16) * F2))[lane];
#pragma unroll
        for (int t = 0; t < 8; ++t) {
            float v = pe_val(p[t]);
            float4 s = fp8x4_dec(u[t]);
            float4& a = (t & 3) == 0 ? a0 : (t & 3) == 1 ? a1 : (t & 3) == 2 ? a2 : a3;
            a.x += v * s.x; a.y += v * s.y; a.z += v * s.z; a.w += v * s.w;
        }
    }
    for (; j < end; ++j) {
        unsigned int p = epack[j];
        unsigned int u = ((const unsigned int*)(xw8 + (size_t)(p >> 16) * F2))[lane];
        float v = pe_val(p);
        float4 s = fp8x4_dec(u);
        a0.x += v * s.x; a0.y += v * s.y; a0.z += v * s.z; a0.w += v * s.w;
    }
    float4 a;
    a.x = a0.x + a1.x + a2.x + a3.x;
    a.y = a0.y + a1.y + a2.y + a3.y;
    a.z = a0.z + a1.z + a2.z + a3.z;
    a.w = a0.w + a1.w + a2.w + a3.w;

    a.x = fmaxf(a.x, 0.f); a.y = fmaxf(a.y, 0.f);
    a.z = fmaxf(a.z, 0.f); a.w = fmaxf(a.w, 0.f);

    float m = fmaxf(fmaxf(a.x, a.y), fmaxf(a.z, a.w));
#pragma unroll
    for (int off = 16; off; off >>= 1) m = fmaxf(m, __shfl_xor(m, off));
    float ex = __expf(a.x - m), ey = __expf(a.y - m);
    float ez = __expf(a.z - m), ew = __expf(a.w - m);
    float ssum = ex + ey + ez + ew;
#pragma unroll
    for (int off = 16; off; off >>= 1) ssum += __shfl_xor(ssum, off);
    float inv = 1.f / ssum;

    bool isP = lane < 32;
    float wx = isP ? ex * inv : a.x;
    float wy = isP ? ey * inv : a.y;
    float wz = isP ? ez * inv : a.z;
    float ww = isP ? ew * inv : a.w;
    ((uint2*)(pqh + (size_t)row * F2))[lane] =
        make_uint2(f2_to_h2u(wx, wy), f2_to_h2u(wz, ww));
    if (isP) {
        unsigned int pk = (unsigned int)f32_to_fp8(wx * 256.f)
                        | ((unsigned int)f32_to_fp8(wy * 256.f) << 8)
                        | ((unsigned int)f32_to_fp8(wz * 256.f) << 16)
                        | ((unsigned int)f32_to_fp8(ww * 256.f) << 24);
        ((unsigned int*)(s8 + (size_t)row * KC))[lane] = pk;
    }
}

// ---------------------------------------------------------------------------
// K4: AS = A @ S via fp8 gather of s8 (=256*S); 8-deep pipeline.
// ---------------------------------------------------------------------------
__global__ __launch_bounds__(256) void spmm_s_csr(
    const int* __restrict__ row_start, const unsigned int* __restrict__ epack,
    const unsigned char* __restrict__ s8, __half* __restrict__ ash, int n_nodes)
{
    int row = blockIdx.x * 4 + (threadIdx.x >> 6);
    if (row >= n_nodes) return;
    int lane = threadIdx.x & 63;
    int beg = row_start[row], end = row_start[row + 1];

    float2 a0 = {0,0}, a1 = {0,0}, a2 = {0,0}, a3 = {0,0};
    int j = beg;
    for (; j + 7 < end; j += 8) {
        unsigned int p[8];
#pragma unroll
        for (int t = 0; t < 8; ++t) p[t] = epack[j + t];
        unsigned int u[8];
#pragma unroll
        for (int t = 0; t < 8; ++t)
            u[t] = ((const unsigned short*)(s8 + (size_t)(p[t] >> 16) * KC))[lane];
#pragma unroll
        for (int t = 0; t < 8; ++t) {
            float v = pe_val(p[t]) * (1.f / 256.f);
            float2 f = fp8x2_dec(u[t]);
            float2& a = (t & 3) == 0 ? a0 : (t & 3) == 1 ? a1 : (t & 3) == 2 ? a2 : a3;
            a.x += v * f.x; a.y += v * f.y;
        }
    }
    for (; j < end; ++j) {
        unsigned int p = epack[j];
        unsigned int u = ((const unsigned short*)(s8 + (size_t)(p >> 16) * KC))[lane];
        float v = pe_val(p) * (1.f / 256.f);
        float2 f = fp8x2_dec(u);
        a0.x += v * f.x; a0.y += v * f.y;
    }
    float rx = a0.x + a1.x + a2.x + a3.x;
    float ry = a0.y + a1.y + a2.y + a3.y;
    union { __half2 h; unsigned int i; } o;
    o.h = __floats2half2_rn(rx, ry);
    ((unsigned int*)(ash + (size_t)row * KC))[lane] = o.i;
}

// ---------------------------------------------------------------------------
// K5a: coarse partials via MFMA. which = blockIdx.y (0: S^T@AS, 1: S^T@Z).
// ---------------------------------------------------------------------------
__global__ __launch_bounds__(256) void coarse_part_mfma(
    const __half* __restrict__ pqh, const __half* __restrict__ ash,
    float* __restrict__ part, int n_nodes)
{
    __shared__ _Float16 sSt[128 * LR];   // S^T: [cluster m][node k]
    __shared__ _Float16 sVt[128 * LR];   // V^T: [feat f][node k]
    const int which = blockIdx.y;
    const int tid = threadIdx.x;
    const int w = tid >> 6, lane = tid & 63;
    const int nl = tid & 31;
    const int c0 = (tid >> 5) * 16;
    const int fr = lane & 15;
    const int fk = (lane >> 4) * 8;

    f32x4 acc[2][8];
#pragma unroll
    for (int b = 0; b < 2; ++b)
#pragma unroll
        for (int fb = 0; fb < 8; ++fb) acc[b][fb] = (f32x4){0.f, 0.f, 0.f, 0.f};

    const int stride = gridDim.x * 32;
    for (int n0 = blockIdx.x * 32; n0 < n_nodes; n0 += stride) {
        __syncthreads();
        int n = n0 + nl;
        if (n < n_nodes) {
            uint4 u0 = *(const uint4*)(pqh + (size_t)n * F2 + c0);
            uint4 u1 = *(const uint4*)(pqh + (size_t)n * F2 + c0 + 8);
            store_t16((unsigned short*)sSt, c0, nl, u0, u1);
            uint4 v0, v1;
            if (which) {
                v0 = *(const uint4*)(pqh + (size_t)n * F2 + KC + c0);
                v1 = *(const uint4*)(pqh + (size_t)n * F2 + KC + c0 + 8);
            } else {
                v0 = *(const uint4*)(ash + (size_t)n * KC + c0);
                v1 = *(const uint4*)(ash + (size_t)n * KC + c0 + 8);
            }
            store_t16((unsigned short*)sVt, c0, nl, v0, v1);
        } else {
#pragma unroll
            for (int i = 0; i < 16; ++i) {
                sSt[(c0 + i) * LR + nl] = (_Float16)0.f;
                sVt[(c0 + i) * LR + nl] = (_Float16)0.f;
            }
        }
        __syncthreads();

        f16x8 a0 = *(const f16x8*)(&sSt[((2 * w + 0) * 16 + fr) * LR + fk]);
        f16x8 a1 = *(const f16x8*)(&sSt[((2 * w + 1) * 16 + fr) * LR + fk]);
#pragma unroll
        for (int fb = 0; fb < 8; ++fb) {
            f16x8 bf = *(const f16x8*)(&sVt[(fb * 16 + fr) * LR + fk]);
            acc[0][fb] = __builtin_amdgcn_mfma_f32_16x16x32_f16(a0, bf, acc[0][fb], 0, 0, 0);
            acc[1][fb] = __builtin_amdgcn_mfma_f32_16x16x32_f16(a1, bf, acc[1][fb], 0, 0, 0);
        }
    }

    float* p = part + ((size_t)which * gridDim.x + blockIdx.x) * (KC * KC);
#pragma unroll
    for (int b = 0; b < 2; ++b) {
        int mbase = (2 * w + b) * 16 + (lane >> 4) * 4;
#pragma unroll
        for (int fb = 0; fb < 8; ++fb) {
            int f = fb * 16 + fr;
#pragma unroll
            for (int reg = 0; reg < 4; ++reg)
                p[(size_t)(mbase + reg) * KC + f] = acc[b][fb][reg];
        }
    }
}

// K5b stage 1: part2[s][e] = sum of this split's tiles (grid: 128 x NSPLIT)
__global__ __launch_bounds__(256) void coarse_reduce1(
    const float* __restrict__ part, float* __restrict__ part2, int nb)
{
    int e = blockIdx.x * 256 + threadIdx.x;
    int s = blockIdx.y;
    int which = e >> 14;
    int idx = e & 16383;
    int tpb = nb / NSPLIT;
    const float* p = part + ((size_t)which * nb + (size_t)s * tpb) * (KC * KC) + idx;
    float sum = 0.f;
    for (int t = 0; t < tpb; ++t) sum += p[(size_t)t * (KC * KC)];
    part2[(size_t)s * (2 * KC * KC) + e] = sum;
}

// K5b stage 2: out[e] = sum over NSPLIT partials (full overwrite of d_out)
__global__ __launch_bounds__(256) void coarse_reduce2(
    const float* __restrict__ part2, float* __restrict__ out)
{
    int e = blockIdx.x * 256 + threadIdx.x;
    float s = 0.f;
#pragma unroll
    for (int i = 0; i < NSPLIT; ++i) s += part2[(size_t)i * (2 * KC * KC) + e];
    out[e] = s;
}

// ---------------------------------------------------------------------------
// Fallback f32 atomic path
// ---------------------------------------------------------------------------
__global__ __launch_bounds__(256) void gemm_xw_f(
    const float* __restrict__ x, const float* __restrict__ Wp,
    const float* __restrict__ We, float* __restrict__ xw, int n_nodes)
{
    constexpr int RPB = 32;
    __shared__ float xs[RPB][F_IN];
    const int r0 = blockIdx.x * RPB;
    const int tid = threadIdx.x;
    for (int i = tid; i < RPB * F_IN; i += 256) {
        int r = i >> 7, c = i & 127;
        int gr = r0 + r;
        xs[r][c] = (gr < n_nodes) ? x[(size_t)gr * F_IN + c] : 0.f;
    }
    __syncthreads();
    const int col = tid;
    const float* W = (col < KC) ? (Wp + col) : (We + (col - KC));
    float acc[RPB];
#pragma unroll
    for (int r = 0; r < RPB; ++r) acc[r] = 0.f;
    for (int k = 0; k < F_IN; ++k) {
        float w = W[(size_t)k * KC];
        const float* xk = &xs[0][k];
#pragma unroll
        for (int r = 0; r < RPB; ++r) acc[r] += xk[r * F_IN] * w;
    }
#pragma unroll
    for (int r = 0; r < RPB; ++r) {
        int gr = r0 + r;
        if (gr < n_nodes) xw[(size_t)gr * F2 + col] = acc[r];
    }
}

__global__ __launch_bounds__(256) void spmm_dual_kernel(
    const int* __restrict__ erow, const int* __restrict__ ecol,
    const float* __restrict__ eval_, const float* __restrict__ xw,
    float* __restrict__ pq, int n_edges)
{
    int e = blockIdx.x * 4 + (threadIdx.x >> 6);
    if (e >= n_edges) return;
    int lane = threadIdx.x & 63;
    int r = erow[e], c = ecol[e];
    float v = eval_[e];
    const float4* src = (const float4*)(xw + (size_t)c * F2);
    float* dst = pq + (size_t)r * F2;
    float4 s = src[lane];
    int f = lane * 4;
    atomicAdd(&dst[f + 0], v * s.x);
    atomicAdd(&dst[f + 1], v * s.y);
    atomicAdd(&dst[f + 2], v * s.z);
    atomicAdd(&dst[f + 3], v * s.w);
}

__global__ __launch_bounds__(64) void softmax_relu_kernel(
    float* __restrict__ pq, int n_nodes)
{
    int n = blockIdx.x;
    if (n >= n_nodes) return;
    int lane = threadIdx.x;
    float* p = pq + (size_t)n * F2;
    float a0 = fmaxf(p[lane], 0.f);
    float a1 = fmaxf(p[lane + 64], 0.f);
    float m = fmaxf(a0, a1);
#pragma unroll
    for (int off = 32; off; off >>= 1) m = fmaxf(m, __shfl_xor(m, off));
    float e0 = __expf(a0 - m), e1 = __expf(a1 - m);
    float ssum = e0 + e1;
#pragma unroll
    for (int off = 32; off; off >>= 1) ssum += __shfl_xor(ssum, off);
    float inv = 1.f / ssum;
    p[lane]      = e0 * inv;
    p[lane + 64] = e1 * inv;
    p[lane + 128] = fmaxf(p[lane + 128], 0.f);
    p[lane + 192] = fmaxf(p[lane + 192], 0.f);
}

__global__ __launch_bounds__(256) void spmm_s_kernel(
    const int* __restrict__ erow, const int* __restrict__ ecol,
    const float* __restrict__ eval_, const float* __restrict__ pq,
    float* __restrict__ as_, int n_edges)
{
    int e = blockIdx.x * 4 + (threadIdx.x >> 6);
    if (e >= n_edges) return;
    int lane = threadIdx.x & 63;
    int r = erow[e], c = ecol[e];
    float v = eval_[e];
    const float2* src = (const float2*)(pq + (size_t)c * F2);
    float* dst = as_ + (size_t)r * KC;
    float2 s = src[lane];
    int f = lane * 2;
    atomicAdd(&dst[f + 0], v * s.x);
    atomicAdd(&dst[f + 1], v * s.y);
}

__global__ __launch_bounds__(256) void coarse_f(
    const float* __restrict__ pq, const float* __restrict__ as_,
    float* __restrict__ out, int n_nodes)
{
    const int which = blockIdx.y;
    const int tid = threadIdx.x;
    const int f  = tid & 127;
    const int k0 = (tid >> 7) * 64;
    __shared__ float sS[8][128];
    float acc[64];
#pragma unroll
    for (int i = 0; i < 64; ++i) acc[i] = 0.f;
    const int stride = gridDim.x * 8;
    for (int n0 = blockIdx.x * 8; n0 < n_nodes; n0 += stride) {
        __syncthreads();
        for (int i = tid; i < 8 * 128; i += 256) {
            int rr = i >> 7, cc = i & 127;
            int n = n0 + rr;
            sS[rr][cc] = (n < n_nodes) ? pq[(size_t)n * F2 + cc] : 0.f;
        }
        __syncthreads();
        int rmax = (n_nodes - n0 < 8) ? (n_nodes - n0) : 8;
        for (int rr = 0; rr < rmax; ++rr) {
            int n = n0 + rr;
            float v = which ? pq[(size_t)n * F2 + KC + f]
                            : as_[(size_t)n * KC + f];
            const float4* s4 = (const float4*)(&sS[rr][k0]);
#pragma unroll
            for (int i = 0; i < 16; ++i) {
                float4 sv = s4[i];
                acc[4 * i + 0] += sv.x * v;
                acc[4 * i + 1] += sv.y * v;
                acc[4 * i + 2] += sv.z * v;
                acc[4 * i + 3] += sv.w * v;
            }
        }
    }
    float* o = out + (size_t)which * (KC * KC);
#pragma unroll
    for (int i = 0; i < 64; ++i)
        atomicAdd(&o[(size_t)(k0 + i) * KC + f], acc[i]);
}

// ---------------------------------------------------------------------------
extern "C" void kernel_launch(void* const* d_in, const int* in_sizes, int n_in,
                              void* d_out, int out_size, void* d_ws, size_t ws_size,
                              hipStream_t stream)
{
    const float* x     = (const float*)d_in[0];
    const int*   erow  = (const int*)d_in[1];
    const int*   ecol  = (const int*)d_in[2];
    const float* eval_ = (const float*)d_in[3];
    const float* Wp    = (const float*)d_in[4];
    const float* We    = (const float*)d_in[5];
    float* out = (float*)d_out;

    const int n_nodes = in_sizes[0] / F_IN;
    const int n_edges = in_sizes[1];
    const int nbin = (n_nodes + (1 << BIN_SHIFT) - 1) >> BIN_SHIFT;
    const int M = nbin * NBLK_SORT;
    const int mchunks = (M + 1023) / 1024;
    const int epb = (n_edges + NBLK_SORT - 1) / NBLK_SORT;

    char* base = (char*)d_ws;
    size_t off = 0;
    auto alloc = [&](size_t bytes) -> void* {
        off = (off + 255) & ~(size_t)255;
        void* p = base + off;
        off += bytes;
        return p;
    };
    unsigned char* xw8  = (unsigned char*)alloc((size_t)n_nodes * F2);
    __half* pqh         = (__half*)alloc((size_t)n_nodes * F2 * 2);
    __half* ash         = (__half*)alloc((size_t)n_nodes * KC * 2);
    unsigned char* s8   = (unsigned char*)alloc((size_t)n_nodes * KC);
    int* row_start      = (int*)alloc(((size_t)n_nodes + 1) * 4);
    unsigned int* epack = (unsigned int*)alloc((size_t)n_edges * 4);
    unsigned int* ebin_cv = (unsigned int*)alloc((size_t)n_edges * 4);
    unsigned char* ebin_r8 = (unsigned char*)alloc((size_t)n_edges);
    int* Cmat           = (int*)alloc((size_t)M * 4);
    int* Coff           = (int*)alloc(((size_t)M + 1) * 4);
    int* chunk_sum      = (int*)alloc(1024 * 4);
    int* chunk_base     = (int*)alloc(1024 * 4);
    __half* wt          = (__half*)alloc((size_t)F2 * F_IN * 2);
    float* part         = (float*)alloc((size_t)2 * NB_COARSE * KC * KC * 4);
    float* part2        = (float*)alloc((size_t)NSPLIT * 2 * KC * KC * 4);
    const size_t needed_h = off;

    if (n_nodes <= 65535 && nbin <= MAXBIN && mchunks <= 1024 && ws_size >= needed_h) {
        // ---- fast fp8/fp16 counting-sort + MFMA path ----
        transpose_w<<<F2, 128, 0, stream>>>(Wp, We, wt);
        gemm_xw_mfma<<<(n_nodes + 31) / 32, 256, 0, stream>>>(x, wt, xw8, n_nodes);

        bin_count<<<NBLK_SORT, 256, 0, stream>>>(erow, Cmat, n_edges, nbin, epb);
        scan_local<<<mchunks, 1024, 0, stream>>>(Cmat, Coff, chunk_sum, M);
        scan_chunks<<<1, 1024, 0, stream>>>(chunk_sum, chunk_base, Coff, mchunks, M);
        scan_add<<<(M + 255) / 256, 256, 0, stream>>>(Coff, chunk_base, M);
        bin_place<<<NBLK_SORT, 256, 0, stream>>>(erow, ecol, eval_, Coff,
                                                 ebin_cv, ebin_r8, n_edges, nbin, epb);
        bin_final<<<nbin, 256, 0, stream>>>(ebin_cv, ebin_r8, Coff, epack,
                                            row_start, n_nodes, nbin);

        spmm_dual_csr<<<(n_nodes + 3) / 4, 256, 0, stream>>>(
            row_start, epack, xw8, pqh, s8, n_nodes);
        spmm_s_csr<<<(n_nodes + 3) / 4, 256, 0, stream>>>(
            row_start, epack, s8, ash, n_nodes);

        coarse_part_mfma<<<dim3(NB_COARSE, 2), 256, 0, stream>>>(pqh, ash, part, n_nodes);
        coarse_reduce1<<<dim3((2 * KC * KC) / 256, NSPLIT), 256, 0, stream>>>(
            part, part2, NB_COARSE);
        coarse_reduce2<<<(2 * KC * KC) / 256, 256, 0, stream>>>(part2, out);
    } else {
        // ---- f32 atomic fallback ----
        float* xw  = (float*)d_ws;
        float* pq  = xw + (size_t)n_nodes * F2;
        float* as_ = xw;
        hipMemsetAsync(d_out, 0, (size_t)out_size * sizeof(float), stream);
        gemm_xw_f<<<(n_nodes + 31) / 32, 256, 0, stream>>>(x, Wp, We, xw, n_nodes);
        hipMemsetAsync(pq, 0, (size_t)n_nodes * F2 * sizeof(float), stream);
        spmm_dual_kernel<<<(n_edges + 3) / 4, 256, 0, stream>>>(
            erow, ecol, eval_, xw, pq, n_edges);
        softmax_relu_kernel<<<n_nodes, 64, 0, stream>>>(pq, n_nodes);
        hipMemsetAsync(as_, 0, (size_t)n_nodes * KC * sizeof(float), stream);
        spmm_s_kernel<<<(n_edges + 3) / 4, 256, 0, stream>>>(
            erow, ecol, eval_, pq, as_, n_edges);
        coarse_f<<<dim3(128, 2), 256, 0, stream>>>(pq, as_, out, n_nodes);
    }
}

// Round 12
// 217.843 us; speedup vs baseline: 1.0968x; 1.0135x over previous
//
#include <hip/hip_runtime.h>
#include <hip/hip_fp16.h>

constexpr int F_IN = 128;
constexpr int KC   = 128;   // K_CLUST == F_EMB == 128
constexpr int F2   = 256;   // K_CLUST + F_EMB
constexpr int NB_COARSE = 256;   // partial tiles per output
constexpr int NSPLIT = 8;        // t-axis split in coarse reduce stage 1
constexpr int NBLK_SORT = 256;   // blocks in bin-count / bin-place passes
constexpr int BIN_SHIFT = 6;     // 64 rows per bin (R12: was 7; 2x bin_final parallelism)
constexpr int MAXBIN = 1024;     // ceil(65536/64)
constexpr int LR = 40;           // LDS row stride (fp16 units); 80B = 5*16B

typedef _Float16 f16x8 __attribute__((ext_vector_type(8)));
typedef float    f32x4 __attribute__((ext_vector_type(4)));
typedef float    f32x2 __attribute__((ext_vector_type(2)));

// ---------- fp16 helpers ----------
__device__ __forceinline__ unsigned int f2_to_h2u(float x, float y) {
    union { __half2 h; unsigned int i; } c;
    c.h = __floats2half2_rn(x, y);
    return c.i;
}
__device__ __forceinline__ float pe_val(unsigned int pe) {
    return __half2float(__ushort_as_half((unsigned short)(pe & 0xffffu)));
}

// ---------- fp8 e4m3fn helpers ----------
__device__ __forceinline__ unsigned char f32_to_fp8(float f) {
    union { __half h; unsigned short u; } c; c.h = __float2half_rn(f);
    unsigned short h = c.u;
    unsigned int s = (h >> 8) & 0x80u;
    int e5 = (h >> 10) & 0x1f;
    if (e5 < 9) return (unsigned char)s;
    unsigned int c7 = ((unsigned int)(e5 - 8) << 3) | ((h >> 7) & 7u);
    unsigned int rem = h & 0x7fu;
    c7 += (rem > 0x40u) || ((rem == 0x40u) && (c7 & 1u));
    if (c7 > 0x7eu) c7 = 0x7eu;
    return (unsigned char)(s | c7);
}
__device__ __forceinline__ float4 fp8x4_dec(unsigned int u) {
#if __has_builtin(__builtin_amdgcn_cvt_pk_f32_fp8)
    f32x2 lo = __builtin_amdgcn_cvt_pk_f32_fp8((int)u, false);
    f32x2 hi = __builtin_amdgcn_cvt_pk_f32_fp8((int)u, true);
    return make_float4(lo.x, lo.y, hi.x, hi.y);
#else
    unsigned int e01 = (u & 0xffu) | ((u & 0xff00u) << 8);
    unsigned int e23 = ((u >> 16) & 0xffu) | ((u & 0xff000000u) >> 8);
    unsigned int h01 = ((e01 & 0x00800080u) << 8) | (((e01 & 0x007f007fu) << 7) + 0x20002000u);
    unsigned int h23 = ((e23 & 0x00800080u) << 8) | (((e23 & 0x007f007fu) << 7) + 0x20002000u);
    union { unsigned int i; __half2 h; } t0, t1;
    t0.i = h01; t1.i = h23;
    float2 f0 = __half22float2(t0.h), f1 = __half22float2(t1.h);
    return make_float4(f0.x, f0.y, f1.x, f1.y);
#endif
}
__device__ __forceinline__ float2 fp8x2_dec(unsigned int u) {
#if __has_builtin(__builtin_amdgcn_cvt_pk_f32_fp8)
    f32x2 lo = __builtin_amdgcn_cvt_pk_f32_fp8((int)u, false);
    return make_float2(lo.x, lo.y);
#else
    unsigned int e01 = (u & 0xffu) | ((u & 0xff00u) << 8);
    unsigned int h01 = ((e01 & 0x00800080u) << 8) | (((e01 & 0x007f007fu) << 7) + 0x20002000u);
    union { unsigned int i; __half2 h; } t0;
    t0.i = h01;
    float2 f0 = __half22float2(t0.h);
    return f0;
#endif
}

// scatter-transpose 16 fp16 (from two uint4) into column nl of LDS tile
__device__ __forceinline__ void store_t16(unsigned short* dst, int c0, int nl,
                                          uint4 u0, uint4 u1) {
    unsigned int w[8] = {u0.x, u0.y, u0.z, u0.w, u1.x, u1.y, u1.z, u1.w};
#pragma unroll
    for (int i = 0; i < 8; ++i) {
        dst[(c0 + 2 * i) * LR + nl]     = (unsigned short)(w[i] & 0xffffu);
        dst[(c0 + 2 * i + 1) * LR + nl] = (unsigned short)(w[i] >> 16);
    }
}

// ---------------------------------------------------------------------------
// W transpose: wt[col][k] = W[k][col], fp16.
// ---------------------------------------------------------------------------
__global__ __launch_bounds__(128) void transpose_w(
    const float* __restrict__ Wp, const float* __restrict__ We,
    __half* __restrict__ wt)
{
    int col = blockIdx.x;
    int k   = threadIdx.x;
    float v = (col < KC) ? Wp[(size_t)k * KC + col]
                         : We[(size_t)k * KC + (col - KC)];
    wt[(size_t)col * F_IN + k] = __float2half_rn(v);
}

// ---------------------------------------------------------------------------
// K1: XW = x @ [W_pool | W_embed] -> fp8 [N,256], via MFMA 16x16x32_f16.
// ---------------------------------------------------------------------------
__global__ __launch_bounds__(256) void gemm_xw_mfma(
    const float* __restrict__ x, const __half* __restrict__ wt,
    unsigned char* __restrict__ xw8, int n_nodes)
{
    __shared__ _Float16 xs[32][136];
    const int r0 = blockIdx.x * 32;
    const int tid = threadIdx.x;
    {
        int r = tid >> 3, c0 = (tid & 7) * 16;
        int gr = r0 + r;
        if (gr < n_nodes) {
            const float4* src = (const float4*)(x + (size_t)gr * F_IN + c0);
#pragma unroll
            for (int i = 0; i < 4; ++i) {
                float4 f = src[i];
                xs[r][c0 + 4 * i + 0] = (_Float16)f.x;
                xs[r][c0 + 4 * i + 1] = (_Float16)f.y;
                xs[r][c0 + 4 * i + 2] = (_Float16)f.z;
                xs[r][c0 + 4 * i + 3] = (_Float16)f.w;
            }
        } else {
#pragma unroll
            for (int i = 0; i < 16; ++i) xs[r][c0 + i] = (_Float16)0.f;
        }
    }
    __syncthreads();

    const int w = tid >> 6, lane = tid & 63;
    const int lrow = lane & 15;
    const int lk   = (lane >> 4) * 8;

    f16x8 bfrag[4][4];
#pragma unroll
    for (int cb = 0; cb < 4; ++cb) {
        int gcol = (w * 4 + cb) * 16 + lrow;
        const f16x8* bp = (const f16x8*)(wt + (size_t)gcol * F_IN + lk);
#pragma unroll
        for (int kc = 0; kc < 4; ++kc) bfrag[cb][kc] = bp[kc * 4];
    }

    f32x4 acc[2][4];
#pragma unroll
    for (int rb = 0; rb < 2; ++rb)
#pragma unroll
        for (int cb = 0; cb < 4; ++cb) acc[rb][cb] = (f32x4){0.f, 0.f, 0.f, 0.f};

#pragma unroll
    for (int kc = 0; kc < 4; ++kc) {
        f16x8 a0 = *(const f16x8*)(&xs[lrow][kc * 32 + lk]);
        f16x8 a1 = *(const f16x8*)(&xs[16 + lrow][kc * 32 + lk]);
#pragma unroll
        for (int cb = 0; cb < 4; ++cb) {
            acc[0][cb] = __builtin_amdgcn_mfma_f32_16x16x32_f16(a0, bfrag[cb][kc], acc[0][cb], 0, 0, 0);
            acc[1][cb] = __builtin_amdgcn_mfma_f32_16x16x32_f16(a1, bfrag[cb][kc], acc[1][cb], 0, 0, 0);
        }
    }

#pragma unroll
    for (int rb = 0; rb < 2; ++rb) {
#pragma unroll
        for (int cb = 0; cb < 4; ++cb) {
            int gcol = (w * 4 + cb) * 16 + lrow;
#pragma unroll
            for (int reg = 0; reg < 4; ++reg) {
                int grow = r0 + rb * 16 + (lane >> 4) * 4 + reg;
                if (grow < n_nodes)
                    xw8[(size_t)grow * F2 + gcol] = f32_to_fp8(acc[rb][cb][reg]);
            }
        }
    }
}

// ---------------------------------------------------------------------------
// Two-level counting sort (row bins of 64), no global cursors.
// ---------------------------------------------------------------------------
__global__ __launch_bounds__(256) void bin_count(
    const int* __restrict__ erow, int* __restrict__ Cmat,
    int n_edges, int nbin, int epb)
{
    __shared__ int bc[MAXBIN];
    const int tid = threadIdx.x, blk = blockIdx.x;
    for (int i = tid; i < nbin; i += 256) bc[i] = 0;
    __syncthreads();
    int e0 = blk * epb;
    int e1 = min(e0 + epb, n_edges);
    for (int e = e0 + tid; e < e1; e += 256)
        atomicAdd(&bc[erow[e] >> BIN_SHIFT], 1);
    __syncthreads();
    for (int i = tid; i < nbin; i += 256)
        Cmat[i * NBLK_SORT + blk] = bc[i];
}

__global__ __launch_bounds__(1024) void scan_local(
    int* __restrict__ cnt, int* __restrict__ row_start,
    int* __restrict__ chunk_sum, int n)
{
    __shared__ int wsum[16];
    const int tid = threadIdx.x;
    const int lane = tid & 63, wid = tid >> 6;
    int i = blockIdx.x * 1024 + tid;
    int v = (i < n) ? cnt[i] : 0;
    int incl = v;
#pragma unroll
    for (int off = 1; off < 64; off <<= 1) {
        int t = __shfl_up(incl, off);
        if (lane >= off) incl += t;
    }
    if (lane == 63) wsum[wid] = incl;
    __syncthreads();
    if (tid == 0) {
        int s = 0;
#pragma unroll
        for (int w = 0; w < 16; ++w) { int t = wsum[w]; wsum[w] = s; s += t; }
    }
    __syncthreads();
    if (i < n) row_start[i] = wsum[wid] + incl - v;
    if (tid == 1023) chunk_sum[blockIdx.x] = wsum[15] + incl;
}

__global__ __launch_bounds__(1024) void scan_chunks(
    const int* __restrict__ chunk_sum, int* __restrict__ chunk_base,
    int* __restrict__ row_start, int nchunks, int n)
{
    __shared__ int wsum[16];
    const int tid = threadIdx.x;
    const int lane = tid & 63, wid = tid >> 6;
    int v = (tid < nchunks) ? chunk_sum[tid] : 0;
    int incl = v;
#pragma unroll
    for (int off = 1; off < 64; off <<= 1) {
        int t = __shfl_up(incl, off);
        if (lane >= off) incl += t;
    }
    if (lane == 63) wsum[wid] = incl;
    __syncthreads();
    if (tid == 0) {
        int s = 0;
#pragma unroll
        for (int w = 0; w < 16; ++w) { int t = wsum[w]; wsum[w] = s; s += t; }
    }
    __syncthreads();
    int excl = wsum[wid] + incl - v;
    if (tid < nchunks) chunk_base[tid] = excl;
    if (tid == nchunks - 1) row_start[n] = excl + v;
}

__global__ __launch_bounds__(256) void scan_add(
    int* __restrict__ row_start, const int* __restrict__ chunk_base, int n)
{
    int i = blockIdx.x * 256 + threadIdx.x;
    if (i < n) row_start[i] += chunk_base[i >> 10];
}

__global__ __launch_bounds__(256) void bin_place(
    const int* __restrict__ erow, const int* __restrict__ ecol,
    const float* __restrict__ eval_, const int* __restrict__ Coff,
    unsigned int* __restrict__ ebin_cv, unsigned char* __restrict__ ebin_r8,
    int n_edges, int nbin, int epb)
{
    __shared__ int curs[MAXBIN];
    const int tid = threadIdx.x, blk = blockIdx.x;
    for (int i = tid; i < nbin; i += 256) curs[i] = Coff[i * NBLK_SORT + blk];
    __syncthreads();
    int e0 = blk * epb;
    int e1 = min(e0 + epb, n_edges);
    for (int e = e0 + tid; e < e1; e += 256) {
        int r = erow[e];
        int b = r >> BIN_SHIFT;
        int pos = atomicAdd(&curs[b], 1);
        union { __half h; unsigned short u; } hv;
        hv.h = __float2half_rn(eval_[e]);
        ebin_cv[pos] = ((unsigned int)ecol[e] << 16) | (unsigned int)hv.u;
        ebin_r8[pos] = (unsigned char)(r & ((1 << BIN_SHIFT) - 1));
    }
}

// Pass D: one block per 64-row bin. LDS row-hist -> local scan -> row_start;
// final place into exact CSR slots.
__global__ __launch_bounds__(256) void bin_final(
    const unsigned int* __restrict__ ebin_cv, const unsigned char* __restrict__ ebin_r8,
    const int* __restrict__ Coff, unsigned int* __restrict__ epack,
    int* __restrict__ row_start, int n_nodes, int nbin)
{
    constexpr int RPB = 1 << BIN_SHIFT;
    __shared__ int rcnt[RPB];
    __shared__ int rbase[RPB];
    const int bin = blockIdx.x, tid = threadIdx.x;
    const int beg = Coff[(size_t)bin * NBLK_SORT];
    const int end = Coff[(size_t)(bin + 1) * NBLK_SORT];
    if (tid < RPB) rcnt[tid] = 0;
    __syncthreads();
    for (int j = beg + tid; j < end; j += 256)
        atomicAdd(&rcnt[ebin_r8[j]], 1);
    __syncthreads();
    if (tid == 0) {
        int s = 0;
#pragma unroll
        for (int i = 0; i < RPB; ++i) { rbase[i] = s; s += rcnt[i]; }
    }
    __syncthreads();
    int grow = bin * RPB + tid;
    if (tid < RPB && grow < n_nodes) row_start[grow] = beg + rbase[tid];
    if (bin == nbin - 1 && tid == 0) row_start[n_nodes] = end;
    if (tid < RPB) rcnt[tid] = 0;
    __syncthreads();
    for (int j = beg + tid; j < end; j += 256) {
        int r8 = ebin_r8[j];
        int rank = atomicAdd(&rcnt[r8], 1);
        epack[beg + rbase[r8] + rank] = ebin_cv[j];
    }
}

// ---------------------------------------------------------------------------
// K2: CSR SpMM over 256 fp8 cols, one wave/row, fused relu+softmax.
// 8-deep gather pipeline + 4-step tail. Outputs: pqh fp16 (S|Z), s8 fp8.
// ---------------------------------------------------------------------------
__global__ __launch_bounds__(256) void spmm_dual_csr(
    const int* __restrict__ row_start, const unsigned int* __restrict__ epack,
    const unsigned char* __restrict__ xw8, __half* __restrict__ pqh,
    unsigned char* __restrict__ s8, int n_nodes)
{
    int row = blockIdx.x * 4 + (threadIdx.x >> 6);
    if (row >= n_nodes) return;
    int lane = threadIdx.x & 63;
    int beg = row_start[row], end = row_start[row + 1];
    const int lb = lane << 2;   // byte offset of this lane's dword

    float4 a0 = {0,0,0,0}, a1 = {0,0,0,0}, a2 = {0,0,0,0}, a3 = {0,0,0,0};
    int j = beg;
    for (; j + 7 < end; j += 8) {
        unsigned int p[8];
#pragma unroll
        for (int t = 0; t < 8; ++t) p[t] = epack[j + t];
        unsigned int u[8];
#pragma unroll
        for (int t = 0; t < 8; ++t)
            u[t] = *(const unsigned int*)(xw8 + ((p[t] >> 8) & 0xFFFF00u) + lb);
#pragma unroll
        for (int t = 0; t < 8; ++t) {
            float v = pe_val(p[t]);
            float4 s = fp8x4_dec(u[t]);
            float4& a = (t & 3) == 0 ? a0 : (t & 3) == 1 ? a1 : (t & 3) == 2 ? a2 : a3;
            a.x += v * s.x; a.y += v * s.y; a.z += v * s.z; a.w += v * s.w;
        }
    }
    if (j + 3 < end) {
        unsigned int p[4];
#pragma unroll
        for (int t = 0; t < 4; ++t) p[t] = epack[j + t];
        unsigned int u[4];
#pragma unroll
        for (int t = 0; t < 4; ++t)
            u[t] = *(const unsigned int*)(xw8 + ((p[t] >> 8) & 0xFFFF00u) + lb);
#pragma unroll
        for (int t = 0; t < 4; ++t) {
            float v = pe_val(p[t]);
            float4 s = fp8x4_dec(u[t]);
            float4& a = t == 0 ? a0 : t == 1 ? a1 : t == 2 ? a2 : a3;
            a.x += v * s.x; a.y += v * s.y; a.z += v * s.z; a.w += v * s.w;
        }
        j += 4;
    }
    for (; j < end; ++j) {
        unsigned int p = epack[j];
        unsigned int u = *(const unsigned int*)(xw8 + ((p >> 8) & 0xFFFF00u) + lb);
        float v = pe_val(p);
        float4 s = fp8x4_dec(u);
        a0.x += v * s.x; a0.y += v * s.y; a0.z += v * s.z; a0.w += v * s.w;
    }
    float4 a;
    a.x = a0.x + a1.x + a2.x + a3.x;
    a.y = a0.y + a1.y + a2.y + a3.y;
    a.z = a0.z + a1.z + a2.z + a3.z;
    a.w = a0.w + a1.w + a2.w + a3.w;

    a.x = fmaxf(a.x, 0.f); a.y = fmaxf(a.y, 0.f);
    a.z = fmaxf(a.z, 0.f); a.w = fmaxf(a.w, 0.f);

    float m = fmaxf(fmaxf(a.x, a.y), fmaxf(a.z, a.w));
#pragma unroll
    for (int off = 16; off; off >>= 1) m = fmaxf(m, __shfl_xor(m, off));
    float ex = __expf(a.x - m), ey = __expf(a.y - m);
    float ez = __expf(a.z - m), ew = __expf(a.w - m);
    float ssum = ex + ey + ez + ew;
#pragma unroll
    for (int off = 16; off; off >>= 1) ssum += __shfl_xor(ssum, off);
    float inv = 1.f / ssum;

    bool isP = lane < 32;
    float wx = isP ? ex * inv : a.x;
    float wy = isP ? ey * inv : a.y;
    float wz = isP ? ez * inv : a.z;
    float ww = isP ? ew * inv : a.w;
    ((uint2*)(pqh + (size_t)row * F2))[lane] =
        make_uint2(f2_to_h2u(wx, wy), f2_to_h2u(wz, ww));
    if (isP) {
        unsigned int pk = (unsigned int)f32_to_fp8(wx * 256.f)
                        | ((unsigned int)f32_to_fp8(wy * 256.f) << 8)
                        | ((unsigned int)f32_to_fp8(wz * 256.f) << 16)
                        | ((unsigned int)f32_to_fp8(ww * 256.f) << 24);
        ((unsigned int*)(s8 + (size_t)row * KC))[lane] = pk;
    }
}

// ---------------------------------------------------------------------------
// K4: AS = A @ S via fp8 gather of s8 (=256*S); 8-deep pipeline + 4-tail.
// ---------------------------------------------------------------------------
__global__ __launch_bounds__(256) void spmm_s_csr(
    const int* __restrict__ row_start, const unsigned int* __restrict__ epack,
    const unsigned char* __restrict__ s8, __half* __restrict__ ash, int n_nodes)
{
    int row = blockIdx.x * 4 + (threadIdx.x >> 6);
    if (row >= n_nodes) return;
    int lane = threadIdx.x & 63;
    int beg = row_start[row], end = row_start[row + 1];
    const int lb = lane << 1;   // byte offset of this lane's ushort

    float2 a0 = {0,0}, a1 = {0,0}, a2 = {0,0}, a3 = {0,0};
    int j = beg;
    for (; j + 7 < end; j += 8) {
        unsigned int p[8];
#pragma unroll
        for (int t = 0; t < 8; ++t) p[t] = epack[j + t];
        unsigned int u[8];
#pragma unroll
        for (int t = 0; t < 8; ++t)
            u[t] = *(const unsigned short*)(s8 + ((p[t] >> 9) & 0x7FFF80u) + lb);
#pragma unroll
        for (int t = 0; t < 8; ++t) {
            float v = pe_val(p[t]) * (1.f / 256.f);
            float2 f = fp8x2_dec(u[t]);
            float2& a = (t & 3) == 0 ? a0 : (t & 3) == 1 ? a1 : (t & 3) == 2 ? a2 : a3;
            a.x += v * f.x; a.y += v * f.y;
        }
    }
    if (j + 3 < end) {
        unsigned int p[4];
#pragma unroll
        for (int t = 0; t < 4; ++t) p[t] = epack[j + t];
        unsigned int u[4];
#pragma unroll
        for (int t = 0; t < 4; ++t)
            u[t] = *(const unsigned short*)(s8 + ((p[t] >> 9) & 0x7FFF80u) + lb);
#pragma unroll
        for (int t = 0; t < 4; ++t) {
            float v = pe_val(p[t]) * (1.f / 256.f);
            float2 f = fp8x2_dec(u[t]);
            float2& a = t == 0 ? a0 : t == 1 ? a1 : t == 2 ? a2 : a3;
            a.x += v * f.x; a.y += v * f.y;
        }
        j += 4;
    }
    for (; j < end; ++j) {
        unsigned int p = epack[j];
        unsigned int u = *(const unsigned short*)(s8 + ((p >> 9) & 0x7FFF80u) + lb);
        float v = pe_val(p) * (1.f / 256.f);
        float2 f = fp8x2_dec(u);
        a0.x += v * f.x; a0.y += v * f.y;
    }
    float rx = a0.x + a1.x + a2.x + a3.x;
    float ry = a0.y + a1.y + a2.y + a3.y;
    union { __half2 h; unsigned int i; } o;
    o.h = __floats2half2_rn(rx, ry);
    ((unsigned int*)(ash + (size_t)row * KC))[lane] = o.i;
}

// ---------------------------------------------------------------------------
// K5a: coarse partials via MFMA. which = blockIdx.y (0: S^T@AS, 1: S^T@Z).
// ---------------------------------------------------------------------------
__global__ __launch_bounds__(256) void coarse_part_mfma(
    const __half* __restrict__ pqh, const __half* __restrict__ ash,
    float* __restrict__ part, int n_nodes)
{
    __shared__ _Float16 sSt[128 * LR];   // S^T: [cluster m][node k]
    __shared__ _Float16 sVt[128 * LR];   // V^T: [feat f][node k]
    const int which = blockIdx.y;
    const int tid = threadIdx.x;
    const int w = tid >> 6, lane = tid & 63;
    const int nl = tid & 31;
    const int c0 = (tid >> 5) * 16;
    const int fr = lane & 15;
    const int fk = (lane >> 4) * 8;

    f32x4 acc[2][8];
#pragma unroll
    for (int b = 0; b < 2; ++b)
#pragma unroll
        for (int fb = 0; fb < 8; ++fb) acc[b][fb] = (f32x4){0.f, 0.f, 0.f, 0.f};

    const int stride = gridDim.x * 32;
    for (int n0 = blockIdx.x * 32; n0 < n_nodes; n0 += stride) {
        __syncthreads();
        int n = n0 + nl;
        if (n < n_nodes) {
            uint4 u0 = *(const uint4*)(pqh + (size_t)n * F2 + c0);
            uint4 u1 = *(const uint4*)(pqh + (size_t)n * F2 + c0 + 8);
            store_t16((unsigned short*)sSt, c0, nl, u0, u1);
            uint4 v0, v1;
            if (which) {
                v0 = *(const uint4*)(pqh + (size_t)n * F2 + KC + c0);
                v1 = *(const uint4*)(pqh + (size_t)n * F2 + KC + c0 + 8);
            } else {
                v0 = *(const uint4*)(ash + (size_t)n * KC + c0);
                v1 = *(const uint4*)(ash + (size_t)n * KC + c0 + 8);
            }
            store_t16((unsigned short*)sVt, c0, nl, v0, v1);
        } else {
#pragma unroll
            for (int i = 0; i < 16; ++i) {
                sSt[(c0 + i) * LR + nl] = (_Float16)0.f;
                sVt[(c0 + i) * LR + nl] = (_Float16)0.f;
            }
        }
        __syncthreads();

        f16x8 a0 = *(const f16x8*)(&sSt[((2 * w + 0) * 16 + fr) * LR + fk]);
        f16x8 a1 = *(const f16x8*)(&sSt[((2 * w + 1) * 16 + fr) * LR + fk]);
#pragma unroll
        for (int fb = 0; fb < 8; ++fb) {
            f16x8 bf = *(const f16x8*)(&sVt[(fb * 16 + fr) * LR + fk]);
            acc[0][fb] = __builtin_amdgcn_mfma_f32_16x16x32_f16(a0, bf, acc[0][fb], 0, 0, 0);
            acc[1][fb] = __builtin_amdgcn_mfma_f32_16x16x32_f16(a1, bf, acc[1][fb], 0, 0, 0);
        }
    }

    float* p = part + ((size_t)which * gridDim.x + blockIdx.x) * (KC * KC);
#pragma unroll
    for (int b = 0; b < 2; ++b) {
        int mbase = (2 * w + b) * 16 + (lane >> 4) * 4;
#pragma unroll
        for (int fb = 0; fb < 8; ++fb) {
            int f = fb * 16 + fr;
#pragma unroll
            for (int reg = 0; reg < 4; ++reg)
                p[(size_t)(mbase + reg) * KC + f] = acc[b][fb][reg];
        }
    }
}

// K5b stage 1: part2[s][e] = sum of this split's tiles (grid: 128 x NSPLIT)
__global__ __launch_bounds__(256) void coarse_reduce1(
    const float* __restrict__ part, float* __restrict__ part2, int nb)
{
    int e = blockIdx.x * 256 + threadIdx.x;
    int s = blockIdx.y;
    int which = e >> 14;
    int idx = e & 16383;
    int tpb = nb / NSPLIT;
    const float* p = part + ((size_t)which * nb + (size_t)s * tpb) * (KC * KC) + idx;
    float sum = 0.f;
    for (int t = 0; t < tpb; ++t) sum += p[(size_t)t * (KC * KC)];
    part2[(size_t)s * (2 * KC * KC) + e] = sum;
}

// K5b stage 2: out[e] = sum over NSPLIT partials (full overwrite of d_out)
__global__ __launch_bounds__(256) void coarse_reduce2(
    const float* __restrict__ part2, float* __restrict__ out)
{
    int e = blockIdx.x * 256 + threadIdx.x;
    float s = 0.f;
#pragma unroll
    for (int i = 0; i < NSPLIT; ++i) s += part2[(size_t)i * (2 * KC * KC) + e];
    out[e] = s;
}

// ---------------------------------------------------------------------------
// Fallback f32 atomic path
// ---------------------------------------------------------------------------
__global__ __launch_bounds__(256) void gemm_xw_f(
    const float* __restrict__ x, const float* __restrict__ Wp,
    const float* __restrict__ We, float* __restrict__ xw, int n_nodes)
{
    constexpr int RPB = 32;
    __shared__ float xs[RPB][F_IN];
    const int r0 = blockIdx.x * RPB;
    const int tid = threadIdx.x;
    for (int i = tid; i < RPB * F_IN; i += 256) {
        int r = i >> 7, c = i & 127;
        int gr = r0 + r;
        xs[r][c] = (gr < n_nodes) ? x[(size_t)gr * F_IN + c] : 0.f;
    }
    __syncthreads();
    const int col = tid;
    const float* W = (col < KC) ? (Wp + col) : (We + (col - KC));
    float acc[RPB];
#pragma unroll
    for (int r = 0; r < RPB; ++r) acc[r] = 0.f;
    for (int k = 0; k < F_IN; ++k) {
        float w = W[(size_t)k * KC];
        const float* xk = &xs[0][k];
#pragma unroll
        for (int r = 0; r < RPB; ++r) acc[r] += xk[r * F_IN] * w;
    }
#pragma unroll
    for (int r = 0; r < RPB; ++r) {
        int gr = r0 + r;
        if (gr < n_nodes) xw[(size_t)gr * F2 + col] = acc[r];
    }
}

__global__ __launch_bounds__(256) void spmm_dual_kernel(
    const int* __restrict__ erow, const int* __restrict__ ecol,
    const float* __restrict__ eval_, const float* __restrict__ xw,
    float* __restrict__ pq, int n_edges)
{
    int e = blockIdx.x * 4 + (threadIdx.x >> 6);
    if (e >= n_edges) return;
    int lane = threadIdx.x & 63;
    int r = erow[e], c = ecol[e];
    float v = eval_[e];
    const float4* src = (const float4*)(xw + (size_t)c * F2);
    float* dst = pq + (size_t)r * F2;
    float4 s = src[lane];
    int f = lane * 4;
    atomicAdd(&dst[f + 0], v * s.x);
    atomicAdd(&dst[f + 1], v * s.y);
    atomicAdd(&dst[f + 2], v * s.z);
    atomicAdd(&dst[f + 3], v * s.w);
}

__global__ __launch_bounds__(64) void softmax_relu_kernel(
    float* __restrict__ pq, int n_nodes)
{
    int n = blockIdx.x;
    if (n >= n_nodes) return;
    int lane = threadIdx.x;
    float* p = pq + (size_t)n * F2;
    float a0 = fmaxf(p[lane], 0.f);
    float a1 = fmaxf(p[lane + 64], 0.f);
    float m = fmaxf(a0, a1);
#pragma unroll
    for (int off = 32; off; off >>= 1) m = fmaxf(m, __shfl_xor(m, off));
    float e0 = __expf(a0 - m), e1 = __expf(a1 - m);
    float ssum = e0 + e1;
#pragma unroll
    for (int off = 32; off; off >>= 1) ssum += __shfl_xor(ssum, off);
    float inv = 1.f / ssum;
    p[lane]      = e0 * inv;
    p[lane + 64] = e1 * inv;
    p[lane + 128] = fmaxf(p[lane + 128], 0.f);
    p[lane + 192] = fmaxf(p[lane + 192], 0.f);
}

__global__ __launch_bounds__(256) void spmm_s_kernel(
    const int* __restrict__ erow, const int* __restrict__ ecol,
    const float* __restrict__ eval_, const float* __restrict__ pq,
    float* __restrict__ as_, int n_edges)
{
    int e = blockIdx.x * 4 + (threadIdx.x >> 6);
    if (e >= n_edges) return;
    int lane = threadIdx.x & 63;
    int r = erow[e], c = ecol[e];
    float v = eval_[e];
    const float2* src = (const float2*)(pq + (size_t)c * F2);
    float* dst = as_ + (size_t)r * KC;
    float2 s = src[lane];
    int f = lane * 2;
    atomicAdd(&dst[f + 0], v * s.x);
    atomicAdd(&dst[f + 1], v * s.y);
}

__global__ __launch_bounds__(256) void coarse_f(
    const float* __restrict__ pq, const float* __restrict__ as_,
    float* __restrict__ out, int n_nodes)
{
    const int which = blockIdx.y;
    const int tid = threadIdx.x;
    const int f  = tid & 127;
    const int k0 = (tid >> 7) * 64;
    __shared__ float sS[8][128];
    float acc[64];
#pragma unroll
    for (int i = 0; i < 64; ++i) acc[i] = 0.f;
    const int stride = gridDim.x * 8;
    for (int n0 = blockIdx.x * 8; n0 < n_nodes; n0 += stride) {
        __syncthreads();
        for (int i = tid; i < 8 * 128; i += 256) {
            int rr = i >> 7, cc = i & 127;
            int n = n0 + rr;
            sS[rr][cc] = (n < n_nodes) ? pq[(size_t)n * F2 + cc] : 0.f;
        }
        __syncthreads();
        int rmax = (n_nodes - n0 < 8) ? (n_nodes - n0) : 8;
        for (int rr = 0; rr < rmax; ++rr) {
            int n = n0 + rr;
            float v = which ? pq[(size_t)n * F2 + KC + f]
                            : as_[(size_t)n * KC + f];
            const float4* s4 = (const float4*)(&sS[rr][k0]);
#pragma unroll
            for (int i = 0; i < 16; ++i) {
                float4 sv = s4[i];
                acc[4 * i + 0] += sv.x * v;
                acc[4 * i + 1] += sv.y * v;
                acc[4 * i + 2] += sv.z * v;
                acc[4 * i + 3] += sv.w * v;
            }
        }
    }
    float* o = out + (size_t)which * (KC * KC);
#pragma unroll
    for (int i = 0; i < 64; ++i)
        atomicAdd(&o[(size_t)(k0 + i) * KC + f], acc[i]);
}

// ---------------------------------------------------------------------------
extern "C" void kernel_launch(void* const* d_in, const int* in_sizes, int n_in,
                              void* d_out, int out_size, void* d_ws, size_t ws_size,
                              hipStream_t stream)
{
    const float* x     = (const float*)d_in[0];
    const int*   erow  = (const int*)d_in[1];
    const int*   ecol  = (const int*)d_in[2];
    const float* eval_ = (const float*)d_in[3];
    const float* Wp    = (const float*)d_in[4];
    const float* We    = (const float*)d_in[5];
    float* out = (float*)d_out;

    const int n_nodes = in_sizes[0] / F_IN;
    const int n_edges = in_sizes[1];
    const int nbin = (n_nodes + (1 << BIN_SHIFT) - 1) >> BIN_SHIFT;
    const int M = nbin * NBLK_SORT;
    const int mchunks = (M + 1023) / 1024;
    const int epb = (n_edges + NBLK_SORT - 1) / NBLK_SORT;

    char* base = (char*)d_ws;
    size_t off = 0;
    auto alloc = [&](size_t bytes) -> void* {
        off = (off + 255) & ~(size_t)255;
        void* p = base + off;
        off += bytes;
        return p;
    };
    unsigned char* xw8  = (unsigned char*)alloc((size_t)n_nodes * F2);
    __half* pqh         = (__half*)alloc((size_t)n_nodes * F2 * 2);
    __half* ash         = (__half*)alloc((size_t)n_nodes * KC * 2);
    unsigned char* s8   = (unsigned char*)alloc((size_t)n_nodes * KC);
    int* row_start      = (int*)alloc(((size_t)n_nodes + 1) * 4);
    unsigned int* epack = (unsigned int*)alloc((size_t)n_edges * 4);
    unsigned int* ebin_cv = (unsigned int*)alloc((size_t)n_edges * 4);
    unsigned char* ebin_r8 = (unsigned char*)alloc((size_t)n_edges);
    int* Cmat           = (int*)alloc((size_t)M * 4);
    int* Coff           = (int*)alloc(((size_t)M + 1) * 4);
    int* chunk_sum      = (int*)alloc(1024 * 4);
    int* chunk_base     = (int*)alloc(1024 * 4);
    __half* wt          = (__half*)alloc((size_t)F2 * F_IN * 2);
    float* part         = (float*)alloc((size_t)2 * NB_COARSE * KC * KC * 4);
    float* part2        = (float*)alloc((size_t)NSPLIT * 2 * KC * KC * 4);
    const size_t needed_h = off;

    if (n_nodes <= 65535 && nbin <= MAXBIN && mchunks <= 1024 && ws_size >= needed_h) {
        // ---- fast fp8/fp16 counting-sort + MFMA path ----
        transpose_w<<<F2, 128, 0, stream>>>(Wp, We, wt);
        gemm_xw_mfma<<<(n_nodes + 31) / 32, 256, 0, stream>>>(x, wt, xw8, n_nodes);

        bin_count<<<NBLK_SORT, 256, 0, stream>>>(erow, Cmat, n_edges, nbin, epb);
        scan_local<<<mchunks, 1024, 0, stream>>>(Cmat, Coff, chunk_sum, M);
        scan_chunks<<<1, 1024, 0, stream>>>(chunk_sum, chunk_base, Coff, mchunks, M);
        scan_add<<<(M + 255) / 256, 256, 0, stream>>>(Coff, chunk_base, M);
        bin_place<<<NBLK_SORT, 256, 0, stream>>>(erow, ecol, eval_, Coff,
                                                 ebin_cv, ebin_r8, n_edges, nbin, epb);
        bin_final<<<nbin, 256, 0, stream>>>(ebin_cv, ebin_r8, Coff, epack,
                                            row_start, n_nodes, nbin);

        spmm_dual_csr<<<(n_nodes + 3) / 4, 256, 0, stream>>>(
            row_start, epack, xw8, pqh, s8, n_nodes);
        spmm_s_csr<<<(n_nodes + 3) / 4, 256, 0, stream>>>(
            row_start, epack, s8, ash, n_nodes);

        coarse_part_mfma<<<dim3(NB_COARSE, 2), 256, 0, stream>>>(pqh, ash, part, n_nodes);
        coarse_reduce1<<<dim3((2 * KC * KC) / 256, NSPLIT), 256, 0, stream>>>(
            part, part2, NB_COARSE);
        coarse_reduce2<<<(2 * KC * KC) / 256, 256, 0, stream>>>(part2, out);
    } else {
        // ---- f32 atomic fallback ----
        float* xw  = (float*)d_ws;
        float* pq  = xw + (size_t)n_nodes * F2;
        float* as_ = xw;
        hipMemsetAsync(d_out, 0, (size_t)out_size * sizeof(float), stream);
        gemm_xw_f<<<(n_nodes + 31) / 32, 256, 0, stream>>>(x, Wp, We, xw, n_nodes);
        hipMemsetAsync(pq, 0, (size_t)n_nodes * F2 * sizeof(float), stream);
        spmm_dual_kernel<<<(n_edges + 3) / 4, 256, 0, stream>>>(
            erow, ecol, eval_, xw, pq, n_edges);
        softmax_relu_kernel<<<n_nodes, 64, 0, stream>>>(pq, n_nodes);
        hipMemsetAsync(as_, 0, (size_t)n_nodes * KC * sizeof(float), stream);
        spmm_s_kernel<<<(n_edges + 3) / 4, 256, 0, stream>>>(
            erow, ecol, eval_, pq, as_, n_edges);
        coarse_f<<<dim3(128, 2), 256, 0, stream>>>(pq, as_, out, n_nodes);
    }
}